// Round 3
// baseline (1422.396 us; speedup 1.0000x reference)
//
#include <hip/hip_runtime.h>
#include <math.h>

// TransLayer (Nystrom attention) fp32 baseline for MI355X.
// Needs ws_size >= 142,737,416 bytes (35,684,354 floats).

#define NSEQ 8192
#define QLD  1536
#define SCALEQ 0.125f   // 64^-0.5

#define TRWR(ARR, I0, J, V0, V1, V2, V3)                                   \
  ARR[(I0) + 0][J] = V0.x;  ARR[(I0) + 1][J] = V0.y;                       \
  ARR[(I0) + 2][J] = V0.z;  ARR[(I0) + 3][J] = V0.w;                       \
  ARR[(I0) + 4][J] = V1.x;  ARR[(I0) + 5][J] = V1.y;                       \
  ARR[(I0) + 6][J] = V1.z;  ARR[(I0) + 7][J] = V1.w;                       \
  ARR[(I0) + 8][J] = V2.x;  ARR[(I0) + 9][J] = V2.y;                       \
  ARR[(I0) +10][J] = V2.z;  ARR[(I0) +11][J] = V2.w;                       \
  ARR[(I0) +12][J] = V3.x;  ARR[(I0) +13][J] = V3.y;                       \
  ARR[(I0) +14][J] = V3.z;  ARR[(I0) +15][J] = V3.w;

// ---------------- LayerNorm: one wave per 512-wide row ----------------
__global__ __launch_bounds__(64) void ln_kernel(const float* __restrict__ x,
    const float* __restrict__ gamma, const float* __restrict__ beta,
    float* __restrict__ xn) {
  int row = blockIdx.x;
  int t = threadIdx.x;
  const float4* xr = (const float4*)(x + (size_t)row * 512);
  float4 v0 = xr[t];
  float4 v1 = xr[t + 64];
  float s = v0.x + v0.y + v0.z + v0.w + v1.x + v1.y + v1.z + v1.w;
#pragma unroll
  for (int o = 32; o > 0; o >>= 1) s += __shfl_xor(s, o);
  float mu = s * (1.0f / 512.0f);
  float d, q = 0.f;
  d = v0.x - mu; q += d * d;  d = v0.y - mu; q += d * d;
  d = v0.z - mu; q += d * d;  d = v0.w - mu; q += d * d;
  d = v1.x - mu; q += d * d;  d = v1.y - mu; q += d * d;
  d = v1.z - mu; q += d * d;  d = v1.w - mu; q += d * d;
#pragma unroll
  for (int o = 32; o > 0; o >>= 1) q += __shfl_xor(q, o);
  float inv = rsqrtf(q * (1.0f / 512.0f) + 1e-5f);
  const float4* gp = (const float4*)gamma;
  const float4* bp = (const float4*)beta;
  float4 g0 = gp[t], g1 = gp[t + 64], b0 = bp[t], b1 = bp[t + 64];
  float4 o0, o1;
  o0.x = (v0.x - mu) * inv * g0.x + b0.x;
  o0.y = (v0.y - mu) * inv * g0.y + b0.y;
  o0.z = (v0.z - mu) * inv * g0.z + b0.z;
  o0.w = (v0.w - mu) * inv * g0.w + b0.w;
  o1.x = (v1.x - mu) * inv * g1.x + b1.x;
  o1.y = (v1.y - mu) * inv * g1.y + b1.y;
  o1.z = (v1.z - mu) * inv * g1.z + b1.z;
  o1.w = (v1.w - mu) * inv * g1.w + b1.w;
  float4* op = (float4*)(xn + (size_t)row * 512);
  op[t] = o0;
  op[t + 64] = o1;
}

// -------- Tiled GEMM: C[M,N] = A[M,K] @ B[N,K]^T (+ X + bias) ----------
// 128x128 tile, 256 threads, 8x8 per thread (2x2 quadrants of 4x4), BK=16.
// M,N multiples of 128; K multiple of 16.
template <int EPI>
__global__ __launch_bounds__(256) void gemm_bt(
    const float* __restrict__ A, const float* __restrict__ B,
    float* __restrict__ C, int Mdim, int Ndim, int Kdim,
    const float* __restrict__ X, const float* __restrict__ bias) {
  __shared__ float As[16][128];   // [k][m]
  __shared__ float Bs[16][128];   // [k][n]
  int tid = threadIdx.x;
  int tx = tid & 15, ty = tid >> 4;          // 16x16 compute grid
  int mbase = blockIdx.y << 7, nbase = blockIdx.x << 7;
  int lr = tid >> 1;                         // 0..127 tile row
  int lc = (tid & 1) << 3;                   // 0 or 8 (k offset)
  const float* Ap = A + (size_t)(mbase + lr) * Kdim + lc;
  const float* Bp = B + (size_t)(nbase + lr) * Kdim + lc;
  float acc[8][8] = {};
  for (int k0 = 0; k0 < Kdim; k0 += 16) {
    float4 av0 = *(const float4*)(Ap + k0);
    float4 av1 = *(const float4*)(Ap + k0 + 4);
    float4 bv0 = *(const float4*)(Bp + k0);
    float4 bv1 = *(const float4*)(Bp + k0 + 4);
    __syncthreads();
    As[lc + 0][lr] = av0.x; As[lc + 1][lr] = av0.y;
    As[lc + 2][lr] = av0.z; As[lc + 3][lr] = av0.w;
    As[lc + 4][lr] = av1.x; As[lc + 5][lr] = av1.y;
    As[lc + 6][lr] = av1.z; As[lc + 7][lr] = av1.w;
    Bs[lc + 0][lr] = bv0.x; Bs[lc + 1][lr] = bv0.y;
    Bs[lc + 2][lr] = bv0.z; Bs[lc + 3][lr] = bv0.w;
    Bs[lc + 4][lr] = bv1.x; Bs[lc + 5][lr] = bv1.y;
    Bs[lc + 6][lr] = bv1.z; Bs[lc + 7][lr] = bv1.w;
    __syncthreads();
#pragma unroll
    for (int kk = 0; kk < 16; ++kk) {
      float4 a0 = *(const float4*)&As[kk][ty * 4];
      float4 a1 = *(const float4*)&As[kk][64 + ty * 4];
      float4 b0 = *(const float4*)&Bs[kk][tx * 4];
      float4 b1 = *(const float4*)&Bs[kk][64 + tx * 4];
      float avr[8] = {a0.x, a0.y, a0.z, a0.w, a1.x, a1.y, a1.z, a1.w};
      float bvr[8] = {b0.x, b0.y, b0.z, b0.w, b1.x, b1.y, b1.z, b1.w};
#pragma unroll
      for (int i = 0; i < 8; ++i)
#pragma unroll
        for (int j = 0; j < 8; ++j) acc[i][j] += avr[i] * bvr[j];
    }
  }
#pragma unroll
  for (int iq = 0; iq < 2; ++iq) {
#pragma unroll
    for (int i = 0; i < 4; ++i) {
      int m = mbase + iq * 64 + ty * 4 + i;
#pragma unroll
      for (int jq = 0; jq < 2; ++jq) {
        int n = nbase + jq * 64 + tx * 4;
        float4 c4;
        c4.x = acc[iq * 4 + i][jq * 4 + 0];
        c4.y = acc[iq * 4 + i][jq * 4 + 1];
        c4.z = acc[iq * 4 + i][jq * 4 + 2];
        c4.w = acc[iq * 4 + i][jq * 4 + 3];
        if (EPI == 1) {
          float4 x4 = *(const float4*)(X + (size_t)m * Ndim + n);
          float4 bb = *(const float4*)(bias + n);
          c4.x += x4.x + bb.x; c4.y += x4.y + bb.y;
          c4.z += x4.z + bb.z; c4.w += x4.w + bb.w;
        }
        *(float4*)(C + (size_t)m * Ndim + n) = c4;
      }
    }
  }
}

// ---------------- Batched mm (16 batches): C = acoef*(A@B) + ecoef*E ----
// A [bh][256][256], B [bh][256][Ndim], C/E [bh][256][Ndim]. K fixed = 256.
__global__ __launch_bounds__(256) void bmm_kernel(
    const float* __restrict__ A, const float* __restrict__ B,
    float* __restrict__ C, int Ndim,
    const float* __restrict__ E, float ecoef, float acoef) {
  int bh = blockIdx.z;
  const float* Ab = A + ((size_t)bh << 16);
  const float* Bb = B + (size_t)bh * 256 * Ndim;
  float* Cb = C + (size_t)bh * 256 * Ndim;
  const float* Eb = E ? (E + (size_t)bh * 256 * Ndim) : nullptr;
  __shared__ float As[16][64];
  __shared__ float Bs[16][64];
  int tid = threadIdx.x;
  int tx = tid & 15, ty = tid >> 4;
  int mbase = blockIdx.y << 6, nbase = blockIdx.x << 6;
  int lr = tid >> 2, lc = tid & 3;
  int bk = tid >> 6, bn = tid & 63;
  float acc[4][4] = {};
  for (int k0 = 0; k0 < 256; k0 += 16) {
    float4 av = *(const float4*)(Ab + (size_t)(mbase + lr) * 256 + k0 + lc * 4);
    float b0 = Bb[(size_t)(k0 + bk) * Ndim + nbase + bn];
    float b1 = Bb[(size_t)(k0 + bk + 4) * Ndim + nbase + bn];
    float b2 = Bb[(size_t)(k0 + bk + 8) * Ndim + nbase + bn];
    float b3 = Bb[(size_t)(k0 + bk + 12) * Ndim + nbase + bn];
    __syncthreads();
    As[lc * 4 + 0][lr] = av.x; As[lc * 4 + 1][lr] = av.y;
    As[lc * 4 + 2][lr] = av.z; As[lc * 4 + 3][lr] = av.w;
    Bs[bk][bn] = b0; Bs[bk + 4][bn] = b1;
    Bs[bk + 8][bn] = b2; Bs[bk + 12][bn] = b3;
    __syncthreads();
#pragma unroll
    for (int kk = 0; kk < 16; ++kk) {
      float4 a4 = *(const float4*)&As[kk][ty * 4];
      float4 b4 = *(const float4*)&Bs[kk][tx * 4];
      acc[0][0] += a4.x * b4.x; acc[0][1] += a4.x * b4.y;
      acc[0][2] += a4.x * b4.z; acc[0][3] += a4.x * b4.w;
      acc[1][0] += a4.y * b4.x; acc[1][1] += a4.y * b4.y;
      acc[1][2] += a4.y * b4.z; acc[1][3] += a4.y * b4.w;
      acc[2][0] += a4.z * b4.x; acc[2][1] += a4.z * b4.y;
      acc[2][2] += a4.z * b4.z; acc[2][3] += a4.z * b4.w;
      acc[3][0] += a4.w * b4.x; acc[3][1] += a4.w * b4.y;
      acc[3][2] += a4.w * b4.z; acc[3][3] += a4.w * b4.w;
    }
  }
#pragma unroll
  for (int i = 0; i < 4; ++i) {
    int m = mbase + ty * 4 + i;
#pragma unroll
    for (int j = 0; j < 4; ++j) {
      int n = nbase + tx * 4 + j;
      float c = acoef * acc[i][j];
      if (Eb) c += ecoef * Eb[(size_t)m * Ndim + n];
      Cb[(size_t)m * Ndim + n] = c;
    }
  }
}

// ---------------- landmark mean pooling (q scaled) ----------------
__global__ __launch_bounds__(64) void landmarks_kernel(const float* __restrict__ qkv,
    float* __restrict__ ql, float* __restrict__ kl) {
  int blk = blockIdx.x;          // bh*256 + m
  int m = blk & 255, bh = blk >> 8;
  int b = bh >> 3, h = bh & 7;
  int d = threadIdx.x;
  const float* base = qkv + (size_t)(b * NSEQ + m * 32) * QLD + h * 64 + d;
  float sq = 0.f, sk = 0.f;
#pragma unroll 8
  for (int i = 0; i < 32; ++i) {
    sq += base[(size_t)i * QLD];
    sk += base[(size_t)i * QLD + 512];
  }
  ql[((size_t)bh * 256 + m) * 64 + d] = sq * (0.03125f * SCALEQ);
  kl[((size_t)bh * 256 + m) * 64 + d] = sk * 0.03125f;
}

// ---------------- attn2 = softmax(q_l @ k_l^T) [bh][256][256] ----------
__global__ __launch_bounds__(256) void attn2_kernel(const float* __restrict__ ql,
    const float* __restrict__ kl, float* __restrict__ a) {
  int bh = blockIdx.y;
  int rbase = blockIdx.x << 5;   // 32 rows
  __shared__ float qs[32][68];
  __shared__ float kst[64][68];  // transposed [d][j]
  __shared__ float sall[32][260];
  int tid = threadIdx.x;
  int r = tid >> 3, g = tid & 7;
  {
    const float* src = ql + ((size_t)bh * 256 + rbase + r) * 64 + g * 8;
    *(float4*)&qs[r][g * 8] = *(const float4*)src;
    *(float4*)&qs[r][g * 8 + 4] = *(const float4*)(src + 4);
  }
  int jl = tid >> 2, i0 = (tid & 3) << 4;
  for (int mc = 0; mc < 4; ++mc) {
    __syncthreads();
    {
      const float* src = kl + ((size_t)bh * 256 + mc * 64 + jl) * 64 + i0;
      float4 k0 = *(const float4*)src;
      float4 k1 = *(const float4*)(src + 4);
      float4 k2 = *(const float4*)(src + 8);
      float4 k3 = *(const float4*)(src + 12);
      TRWR(kst, i0, jl, k0, k1, k2, k3)
    }
    __syncthreads();
    float s0 = 0, s1 = 0, s2 = 0, s3 = 0, s4 = 0, s5 = 0, s6 = 0, s7 = 0;
#pragma unroll 8
    for (int d = 0; d < 64; ++d) {
      float qv = qs[r][d];
      float4 ka = *(const float4*)&kst[d][g * 8];
      float4 kb = *(const float4*)&kst[d][g * 8 + 4];
      s0 += qv * ka.x; s1 += qv * ka.y; s2 += qv * ka.z; s3 += qv * ka.w;
      s4 += qv * kb.x; s5 += qv * kb.y; s6 += qv * kb.z; s7 += qv * kb.w;
    }
    float* dstp = &sall[r][mc * 64 + g * 8];
    dstp[0] = s0; dstp[1] = s1; dstp[2] = s2; dstp[3] = s3;
    dstp[4] = s4; dstp[5] = s5; dstp[6] = s6; dstp[7] = s7;
  }
  __syncthreads();
  float mx = -3.0e38f;
#pragma unroll
  for (int k = 0; k < 32; ++k) mx = fmaxf(mx, sall[r][g + (k << 3)]);
  mx = fmaxf(mx, __shfl_xor(mx, 1));
  mx = fmaxf(mx, __shfl_xor(mx, 2));
  mx = fmaxf(mx, __shfl_xor(mx, 4));
  float sum = 0.f;
#pragma unroll
  for (int k = 0; k < 32; ++k) {
    float p = expf(sall[r][g + (k << 3)] - mx);
    sall[r][g + (k << 3)] = p;
    sum += p;
  }
  sum += __shfl_xor(sum, 1);
  sum += __shfl_xor(sum, 2);
  sum += __shfl_xor(sum, 4);
  float inv = 1.0f / sum;
  float* dst = a + ((size_t)bh * 256 + rbase + r) * 256;
#pragma unroll
  for (int k = 0; k < 32; ++k) dst[g + (k << 3)] = sall[r][g + (k << 3)] * inv;
}

// ---------------- pinv scale = max(rowsum)*max(colsum) ----------------
__global__ void scale_init(unsigned* sbuf) {
  if (threadIdx.x < 2) sbuf[threadIdx.x] = 0u;
}

__global__ __launch_bounds__(256) void scale_reduce(const float* __restrict__ a,
    unsigned* __restrict__ sbuf) {
  int bh = blockIdx.x;
  int tid = threadIdx.x;
  const float* ab = a + ((size_t)bh << 16);
  const float* row = ab + (size_t)tid * 256;
  float rs = 0.f;
  for (int j = 0; j < 256; ++j) rs += fabsf(row[j]);
  float cs = 0.f;
  for (int i = 0; i < 256; ++i) cs += fabsf(ab[((size_t)i << 8) + tid]);
#pragma unroll
  for (int o = 32; o > 0; o >>= 1) {
    rs = fmaxf(rs, __shfl_xor(rs, o));
    cs = fmaxf(cs, __shfl_xor(cs, o));
  }
  __shared__ float redr[4], redc[4];
  int w = tid >> 6;
  if ((tid & 63) == 0) { redr[w] = rs; redc[w] = cs; }
  __syncthreads();
  if (tid == 0) {
    float mr = fmaxf(fmaxf(redr[0], redr[1]), fmaxf(redr[2], redr[3]));
    float mc = fmaxf(fmaxf(redc[0], redc[1]), fmaxf(redc[2], redc[3]));
    atomicMax(sbuf + 0, __float_as_uint(mr));
    atomicMax(sbuf + 1, __float_as_uint(mc));
  }
}

__global__ __launch_bounds__(256) void z0_kernel(const float* __restrict__ a,
    const unsigned* __restrict__ sbuf, float* __restrict__ z) {
  float inv = 1.0f / (__uint_as_float(sbuf[0]) * __uint_as_float(sbuf[1]));
  size_t idx = (size_t)blockIdx.x * 256 + threadIdx.x;
  int bh = (int)(idx >> 16);
  int rem = (int)(idx & 65535);
  int i = rem >> 8, j = rem & 255;
  z[idx] = a[((size_t)bh << 16) + ((size_t)j << 8) + i] * inv;
}

// ---------------- kv = softmax(q_l @ k^T) @ v   (flash, split-n x4) ----
__global__ __launch_bounds__(256) void kv_flash(const float* __restrict__ ql,
    const float* __restrict__ qkv, float* __restrict__ po,
    float* __restrict__ pm, float* __restrict__ pl) {
  int sp = blockIdx.x;           // 4 splits of 2048
  int mt = blockIdx.y;           // 16 tiles of 16 rows
  int bh = blockIdx.z;           // 16
  int b = bh >> 3, h = bh & 7;
  __shared__ float qs[16][68];
  __shared__ float kst[64][68];  // transposed [d][j]
  __shared__ float vs[64][68];   // row-major [j][d]
  __shared__ float ps[16][68];
  int tid = threadIdx.x;
  int r = tid >> 4, g = tid & 15;
  {
    const float* src = ql + ((size_t)bh * 256 + mt * 16 + r) * 64 + g * 4;
    *(float4*)&qs[r][g * 4] = *(const float4*)src;
  }
  const float* kbase = qkv + (size_t)b * NSEQ * QLD + 512 + h * 64;
  const float* vbase = kbase + 512;
  float m_run = -3.0e38f, l_run = 0.f;
  float o0 = 0.f, o1 = 0.f, o2 = 0.f, o3 = 0.f;
  int d0 = g * 4;
  int jl = tid >> 2, i0 = (tid & 3) << 4;
  for (int c0 = sp * 2048; c0 < sp * 2048 + 2048; c0 += 64) {
    __syncthreads();
    {
      const float* ksrc = kbase + (size_t)(c0 + jl) * QLD + i0;
      const float* vsrc = vbase + (size_t)(c0 + jl) * QLD + i0;
      float4 k0 = *(const float4*)ksrc;
      float4 k1 = *(const float4*)(ksrc + 4);
      float4 k2 = *(const float4*)(ksrc + 8);
      float4 k3 = *(const float4*)(ksrc + 12);
      TRWR(kst, i0, jl, k0, k1, k2, k3)
      *(float4*)&vs[jl][i0 + 0]  = *(const float4*)vsrc;
      *(float4*)&vs[jl][i0 + 4]  = *(const float4*)(vsrc + 4);
      *(float4*)&vs[jl][i0 + 8]  = *(const float4*)(vsrc + 8);
      *(float4*)&vs[jl][i0 + 12] = *(const float4*)(vsrc + 12);
    }
    __syncthreads();
    float s0 = 0, s1 = 0, s2 = 0, s3 = 0;
#pragma unroll 8
    for (int d = 0; d < 64; ++d) {
      float qv = qs[r][d];
      float4 k4 = *(const float4*)&kst[d][g * 4];
      s0 += qv * k4.x; s1 += qv * k4.y; s2 += qv * k4.z; s3 += qv * k4.w;
    }
    float mx = fmaxf(fmaxf(s0, s1), fmaxf(s2, s3));
    mx = fmaxf(mx, __shfl_xor(mx, 1));
    mx = fmaxf(mx, __shfl_xor(mx, 2));
    mx = fmaxf(mx, __shfl_xor(mx, 4));
    mx = fmaxf(mx, __shfl_xor(mx, 8));
    float mnew = fmaxf(m_run, mx);
    float p0 = expf(s0 - mnew), p1 = expf(s1 - mnew);
    float p2 = expf(s2 - mnew), p3 = expf(s3 - mnew);
    float psum = p0 + p1 + p2 + p3;
    psum += __shfl_xor(psum, 1);
    psum += __shfl_xor(psum, 2);
    psum += __shfl_xor(psum, 4);
    psum += __shfl_xor(psum, 8);
    float corr = expf(m_run - mnew);
    l_run = l_run * corr + psum;
    m_run = mnew;
    float4 pw; pw.x = p0; pw.y = p1; pw.z = p2; pw.w = p3;
    *(float4*)&ps[r][g * 4] = pw;
    __syncthreads();
    o0 *= corr; o1 *= corr; o2 *= corr; o3 *= corr;
#pragma unroll 8
    for (int j = 0; j < 64; ++j) {
      float p = ps[r][j];
      float4 v4 = *(const float4*)&vs[j][d0];
      o0 += p * v4.x; o1 += p * v4.y; o2 += p * v4.z; o3 += p * v4.w;
    }
  }
  size_t rowi = ((size_t)sp * 16 + bh) * 256 + mt * 16 + r;
  float4 ow; ow.x = o0; ow.y = o1; ow.z = o2; ow.w = o3;
  *(float4*)&po[rowi * 64 + d0] = ow;
  if (g == 0) { pm[rowi] = m_run; pl[rowi] = l_run; }
}

__global__ __launch_bounds__(64) void kv_combine(const float* __restrict__ po,
    const float* __restrict__ pm, const float* __restrict__ pl,
    float* __restrict__ kv) {
  int row = blockIdx.x;          // bh*256 + m  (4096)
  int d = threadIdx.x;
  float m0 = pm[row], m1 = pm[4096 + row], m2 = pm[8192 + row], m3 = pm[12288 + row];
  float mg = fmaxf(fmaxf(m0, m1), fmaxf(m2, m3));
  float w0 = expf(m0 - mg), w1 = expf(m1 - mg), w2 = expf(m2 - mg), w3 = expf(m3 - mg);
  float l = pl[row] * w0 + pl[4096 + row] * w1 + pl[8192 + row] * w2 + pl[12288 + row] * w3;
  float o = po[(size_t)row * 64 + d] * w0
          + po[(size_t)(4096 + row) * 64 + d] * w1
          + po[(size_t)(8192 + row) * 64 + d] * w2
          + po[(size_t)(12288 + row) * 64 + d] * w3;
  kv[(size_t)row * 64 + d] = o / l;
}

// ---------------- depthwise residual conv (kernel 33 over seq) ---------
__global__ __launch_bounds__(256) void conv_kernel(const float* __restrict__ qkv,
    const float* __restrict__ w_res, float* __restrict__ outh) {
  int nt = blockIdx.x;           // 128 tiles of 64 rows
  int bh = blockIdx.y;           // 16
  int b = bh >> 3, h = bh & 7;
  __shared__ float vsh[96][64];
  __shared__ float wsh[33];
  int tid = threadIdx.x;
  if (tid < 33) wsh[tid] = w_res[h * 33 + tid];
  int nbase = nt << 6;
  const float* vb = qkv + (size_t)b * NSEQ * QLD + 1024 + h * 64;
  for (int i = tid; i < 96 * 16; i += 256) {
    int rr = i >> 4, c4 = (i & 15) << 2;
    int n = nbase - 16 + rr;
    float4 val;
    if (n >= 0 && n < NSEQ) val = *(const float4*)(vb + (size_t)n * QLD + c4);
    else { val.x = 0.f; val.y = 0.f; val.z = 0.f; val.w = 0.f; }
    *(float4*)&vsh[rr][c4] = val;
  }
  __syncthreads();
  int d = tid & 63;
  int r0 = tid >> 6;
  for (int r = r0; r < 64; r += 4) {
    float acc = 0.f;
#pragma unroll
    for (int k = 0; k < 33; ++k) acc += vsh[r + k][d] * wsh[k];
    outh[(size_t)(b * NSEQ + nbase + r) * 512 + h * 64 + d] = acc;
  }
}

// ---------------- out += softmax(q @ k_l^T) @ W  ------------------------
__global__ __launch_bounds__(256) void attn1_kernel(const float* __restrict__ qkv,
    const float* __restrict__ kl, const float* __restrict__ Wm,
    float* __restrict__ outh) {
  int bh = blockIdx.y;
  int b = bh >> 3, h = bh & 7;
  int rbase = blockIdx.x << 5;   // 32 rows of n
  __shared__ float qs[32][68];
  __shared__ float buf[64][68];  // k_l transposed for scores; W row-major for PV
  __shared__ float sall[32][260];
  int tid = threadIdx.x;
  int r = tid >> 3, g = tid & 7;
  {
    const float* src = qkv + (size_t)(b * NSEQ + rbase + r) * QLD + h * 64 + g * 8;
    float4 x0 = *(const float4*)src;
    float4 x1 = *(const float4*)(src + 4);
    x0.x *= SCALEQ; x0.y *= SCALEQ; x0.z *= SCALEQ; x0.w *= SCALEQ;
    x1.x *= SCALEQ; x1.y *= SCALEQ; x1.z *= SCALEQ; x1.w *= SCALEQ;
    *(float4*)&qs[r][g * 8] = x0;
    *(float4*)&qs[r][g * 8 + 4] = x1;
  }
  int jl = tid >> 2, i0 = (tid & 3) << 4;
  for (int mc = 0; mc < 4; ++mc) {
    __syncthreads();
    {
      const float* src = kl + ((size_t)bh * 256 + mc * 64 + jl) * 64 + i0;
      float4 k0 = *(const float4*)src;
      float4 k1 = *(const float4*)(src + 4);
      float4 k2 = *(const float4*)(src + 8);
      float4 k3 = *(const float4*)(src + 12);
      TRWR(buf, i0, jl, k0, k1, k2, k3)
    }
    __syncthreads();
    float s0 = 0, s1 = 0, s2 = 0, s3 = 0, s4 = 0, s5 = 0, s6 = 0, s7 = 0;
#pragma unroll 8
    for (int d = 0; d < 64; ++d) {
      float qv = qs[r][d];
      float4 ka = *(const float4*)&buf[d][g * 8];
      float4 kb = *(const float4*)&buf[d][g * 8 + 4];
      s0 += qv * ka.x; s1 += qv * ka.y; s2 += qv * ka.z; s3 += qv * ka.w;
      s4 += qv * kb.x; s5 += qv * kb.y; s6 += qv * kb.z; s7 += qv * kb.w;
    }
    float* dstp = &sall[r][mc * 64 + g * 8];
    dstp[0] = s0; dstp[1] = s1; dstp[2] = s2; dstp[3] = s3;
    dstp[4] = s4; dstp[5] = s5; dstp[6] = s6; dstp[7] = s7;
  }
  __syncthreads();
  float mx = -3.0e38f;
#pragma unroll
  for (int k = 0; k < 32; ++k) mx = fmaxf(mx, sall[r][g + (k << 3)]);
  mx = fmaxf(mx, __shfl_xor(mx, 1));
  mx = fmaxf(mx, __shfl_xor(mx, 2));
  mx = fmaxf(mx, __shfl_xor(mx, 4));
  float sum = 0.f;
#pragma unroll
  for (int k = 0; k < 32; ++k) {
    float p = expf(sall[r][g + (k << 3)] - mx);
    sall[r][g + (k << 3)] = p;
    sum += p;
  }
  sum += __shfl_xor(sum, 1);
  sum += __shfl_xor(sum, 2);
  sum += __shfl_xor(sum, 4);
  float inv = 1.0f / sum;
  float o0 = 0, o1 = 0, o2 = 0, o3 = 0, o4 = 0, o5 = 0, o6 = 0, o7 = 0;
  for (int mc = 0; mc < 4; ++mc) {
    __syncthreads();
    {
      const float* src = Wm + ((size_t)bh * 256 + mc * 64 + jl) * 64 + i0;
      *(float4*)&buf[jl][i0 + 0]  = *(const float4*)src;
      *(float4*)&buf[jl][i0 + 4]  = *(const float4*)(src + 4);
      *(float4*)&buf[jl][i0 + 8]  = *(const float4*)(src + 8);
      *(float4*)&buf[jl][i0 + 12] = *(const float4*)(src + 12);
    }
    __syncthreads();
#pragma unroll 8
    for (int j = 0; j < 64; ++j) {
      float p = sall[r][mc * 64 + j];
      float4 wa = *(const float4*)&buf[j][g * 8];
      float4 wb = *(const float4*)&buf[j][g * 8 + 4];
      o0 += p * wa.x; o1 += p * wa.y; o2 += p * wa.z; o3 += p * wa.w;
      o4 += p * wb.x; o5 += p * wb.y; o6 += p * wb.z; o7 += p * wb.w;
    }
  }
  float* dst = outh + (size_t)(b * NSEQ + rbase + r) * 512 + h * 64 + g * 8;
  float4 e0 = *(float4*)dst;
  float4 e1 = *(float4*)(dst + 4);
  e0.x += o0 * inv; e0.y += o1 * inv; e0.z += o2 * inv; e0.w += o3 * inv;
  e1.x += o4 * inv; e1.y += o5 * inv; e1.z += o6 * inv; e1.w += o7 * inv;
  *(float4*)dst = e0;
  *(float4*)(dst + 4) = e1;
}

// ======================================================================
extern "C" void kernel_launch(void* const* d_in, const int* in_sizes, int n_in,
                              void* d_out, int out_size, void* d_ws, size_t ws_size,
                              hipStream_t stream) {
  (void)in_sizes; (void)n_in; (void)out_size; (void)ws_size;
  const float* x     = (const float*)d_in[0];
  const float* gamma = (const float*)d_in[1];
  const float* beta  = (const float*)d_in[2];
  const float* w_qkv = (const float*)d_in[3];
  const float* w_out = (const float*)d_in[4];
  const float* b_out = (const float*)d_in[5];
  const float* w_res = (const float*)d_in[6];
  float* out = (float*)d_out;
  float* ws = (float*)d_ws;

  float* xn   = ws;                       // 8,388,608 floats (dead after qkv GEMM)
  float* qkv  = ws + 8388608;             // 25,165,824
  float* ql   = ws + 33554432;            // 262,144
  float* kl   = ws + 33816576;            // 262,144
  float* po   = ws + 34078720;            // 1,048,576
  float* pm   = ws + 35127296;            // 16,384
  float* pl   = ws + 35143680;            // 16,384
  float* kv   = ws + 35160064;            // 262,144
  float* Wm   = ws + 35422208;            // 262,144
  unsigned* sbuf = (unsigned*)(ws + 35684352);   // 2
  // pinv temporaries alias the xn region (xn dead after qkv GEMM):
  float* A2 = xn;
  float* Z0 = xn + 1048576;
  float* Z1 = xn + 2097152;
  float* AZ = xn + 3145728;
  float* TT = xn + 4194304;
  float* UU = xn + 5242880;
  // outh aliases xn too (pinv temps dead once Wm is computed):
  float* outh = xn;

  ln_kernel<<<16384, 64, 0, stream>>>(x, gamma, beta, xn);

  gemm_bt<0><<<dim3(1536 / 128, 16384 / 128), 256, 0, stream>>>(
      xn, w_qkv, qkv, 16384, 1536, 512, nullptr, nullptr);

  landmarks_kernel<<<4096, 64, 0, stream>>>(qkv, ql, kl);

  attn2_kernel<<<dim3(8, 16), 256, 0, stream>>>(ql, kl, A2);

  scale_init<<<1, 64, 0, stream>>>(sbuf);
  scale_reduce<<<16, 256, 0, stream>>>(A2, sbuf);
  z0_kernel<<<4096, 256, 0, stream>>>(A2, sbuf, Z0);

  float* zc = Z0;
  float* zn = Z1;
  for (int it = 0; it < 6; ++it) {
    dim3 gb(4, 4, 16);
    // az = a @ z
    bmm_kernel<<<gb, 256, 0, stream>>>(A2, zc, AZ, 256, nullptr, 0.f, 1.f);
    // t = 7*az - az@az            ( = az @ (7I - az) )
    bmm_kernel<<<gb, 256, 0, stream>>>(AZ, AZ, TT, 256, AZ, 7.f, -1.f);
    // u = 15*az - az@t            ( = az @ (15I - t) )
    bmm_kernel<<<gb, 256, 0, stream>>>(AZ, TT, UU, 256, AZ, 15.f, -1.f);
    // z' = 3.25*z - 0.25*z@u      ( = 0.25 * z @ (13I - u) )
    bmm_kernel<<<gb, 256, 0, stream>>>(zc, UU, zn, 256, zc, 3.25f, -0.25f);
    float* t = zc; zc = zn; zn = t;
  }

  kv_flash<<<dim3(4, 16, 16), 256, 0, stream>>>(ql, qkv, po, pm, pl);
  kv_combine<<<4096, 64, 0, stream>>>(po, pm, pl, kv);

  // W = pinv @ kv   [bh][256][64]
  bmm_kernel<<<dim3(1, 4, 16), 256, 0, stream>>>(zc, kv, Wm, 64, nullptr, 0.f, 1.f);

  conv_kernel<<<dim3(128, 16), 256, 0, stream>>>(qkv, w_res, outh);
  attn1_kernel<<<dim3(256, 16), 256, 0, stream>>>(qkv, kl, Wm, outh);

  gemm_bt<1><<<dim3(512 / 128, 16384 / 128), 256, 0, stream>>>(
      outh, w_out, out, 16384, 512, 512, x, b_out);
}

// Round 4
// 1198.007 us; speedup vs baseline: 1.1873x; 1.1873x over previous
//
#include <hip/hip_runtime.h>
#include <math.h>

// TransLayer (Nystrom attention) for MI355X.
// Split-fp16 MFMA for the two dense GEMMs; fp32 elsewhere.
// Needs ws_size >= 142,606,344 bytes (35,651,586 floats).

#define NSEQ 8192
#define QLD  1536
#define SCALEQ 0.125f   // 64^-0.5

typedef _Float16 half_t;
typedef __attribute__((ext_vector_type(8))) _Float16 f16x8;
typedef __attribute__((ext_vector_type(4))) _Float16 f16x4;
typedef __attribute__((ext_vector_type(4))) float f32x4;

#define TRWR(ARR, I0, J, V0, V1, V2, V3)                                   \
  ARR[(I0) + 0][J] = V0.x;  ARR[(I0) + 1][J] = V0.y;                       \
  ARR[(I0) + 2][J] = V0.z;  ARR[(I0) + 3][J] = V0.w;                       \
  ARR[(I0) + 4][J] = V1.x;  ARR[(I0) + 5][J] = V1.y;                       \
  ARR[(I0) + 6][J] = V1.z;  ARR[(I0) + 7][J] = V1.w;                       \
  ARR[(I0) + 8][J] = V2.x;  ARR[(I0) + 9][J] = V2.y;                       \
  ARR[(I0) +10][J] = V2.z;  ARR[(I0) +11][J] = V2.w;                       \
  ARR[(I0) +12][J] = V3.x;  ARR[(I0) +13][J] = V3.y;                       \
  ARR[(I0) +14][J] = V3.z;  ARR[(I0) +15][J] = V3.w;

// ---------------- LayerNorm: one wave per 512-wide row; writes hi/lo fp16 --
__global__ __launch_bounds__(64) void ln_kernel(const float* __restrict__ x,
    const float* __restrict__ gamma, const float* __restrict__ beta,
    half_t* __restrict__ xh, half_t* __restrict__ xl) {
  int row = blockIdx.x;
  int t = threadIdx.x;
  const float4* xr = (const float4*)(x + (size_t)row * 512);
  float4 v0 = xr[t];
  float4 v1 = xr[t + 64];
  float s = v0.x + v0.y + v0.z + v0.w + v1.x + v1.y + v1.z + v1.w;
#pragma unroll
  for (int o = 32; o > 0; o >>= 1) s += __shfl_xor(s, o);
  float mu = s * (1.0f / 512.0f);
  float d, q = 0.f;
  d = v0.x - mu; q += d * d;  d = v0.y - mu; q += d * d;
  d = v0.z - mu; q += d * d;  d = v0.w - mu; q += d * d;
  d = v1.x - mu; q += d * d;  d = v1.y - mu; q += d * d;
  d = v1.z - mu; q += d * d;  d = v1.w - mu; q += d * d;
#pragma unroll
  for (int o = 32; o > 0; o >>= 1) q += __shfl_xor(q, o);
  float inv = rsqrtf(q * (1.0f / 512.0f) + 1e-5f);
  const float4* gp = (const float4*)gamma;
  const float4* bp = (const float4*)beta;
  float4 g0 = gp[t], g1 = gp[t + 64], b0 = bp[t], b1 = bp[t + 64];
  float a[8];
  a[0] = (v0.x - mu) * inv * g0.x + b0.x;
  a[1] = (v0.y - mu) * inv * g0.y + b0.y;
  a[2] = (v0.z - mu) * inv * g0.z + b0.z;
  a[3] = (v0.w - mu) * inv * g0.w + b0.w;
  a[4] = (v1.x - mu) * inv * g1.x + b1.x;
  a[5] = (v1.y - mu) * inv * g1.y + b1.y;
  a[6] = (v1.z - mu) * inv * g1.z + b1.z;
  a[7] = (v1.w - mu) * inv * g1.w + b1.w;
  f16x4 h0, h1, l0, l1;
#pragma unroll
  for (int j = 0; j < 4; ++j) {
    h0[j] = (half_t)a[j];     l0[j] = (half_t)(a[j] - (float)h0[j]);
    h1[j] = (half_t)a[4 + j]; l1[j] = (half_t)(a[4 + j] - (float)h1[j]);
  }
  half_t* hp = xh + (size_t)row * 512 + t * 4;
  half_t* lp = xl + (size_t)row * 512 + t * 4;
  *(f16x4*)hp = h0; *(f16x4*)(hp + 256) = h1;
  *(f16x4*)lp = l0; *(f16x4*)(lp + 256) = l1;
}

// ---------------- fp32 -> (hi, lo) fp16 splitter -----------------------
__global__ __launch_bounds__(256) void split_kernel(const float* __restrict__ src,
    half_t* __restrict__ hi, half_t* __restrict__ lo, int n4) {
  int i = blockIdx.x * 256 + threadIdx.x;
  if (i >= n4) return;
  float4 v = ((const float4*)src)[i];
  f16x4 h, l;
  h[0] = (half_t)v.x; l[0] = (half_t)(v.x - (float)h[0]);
  h[1] = (half_t)v.y; l[1] = (half_t)(v.y - (float)h[1]);
  h[2] = (half_t)v.z; l[2] = (half_t)(v.z - (float)h[2]);
  h[3] = (half_t)v.w; l[3] = (half_t)(v.w - (float)h[3]);
  ((f16x4*)hi)[i] = h;
  ((f16x4*)lo)[i] = l;
}

// -------- Split-fp16 MFMA GEMM: C[M,N] = A[M,K] @ B[N,K]^T (+ X + bias) --
// A,B given as hi/lo fp16 pairs. 128x128 tile, 4 waves (2x2), per-wave 64x64
// = 4x4 fragments of 16x16x32. 3 MFMAs per product (hh + lh + hl).
template <int EPI>
__global__ __launch_bounds__(256) void gemm_mfma(
    const half_t* __restrict__ Ah, const half_t* __restrict__ Al,
    const half_t* __restrict__ Bh, const half_t* __restrict__ Bl,
    float* __restrict__ C, int Ndim, int Kdim,
    const float* __restrict__ X, const float* __restrict__ bias) {
  __shared__ half_t Ash[128][40];
  __shared__ half_t Asl[128][40];
  __shared__ half_t Bsh[128][40];
  __shared__ half_t Bsl[128][40];
  int tid = threadIdx.x;
  int lane = tid & 63;
  int wave = tid >> 6;
  int wr = (wave >> 1) << 6;    // wave row offset (0/64)
  int wc = (wave & 1) << 6;     // wave col offset (0/64)
  int mbase = blockIdx.y << 7, nbase = blockIdx.x << 7;
  int srow = tid >> 2;          // 0..63 (staging row; second pass +64)
  int sseg = (tid & 3) << 3;    // 0,8,16,24 (k halfs)
  int fr = lane & 15;           // fragment row
  int fk = (lane >> 4) << 3;    // fragment k offset
  f32x4 acc[4][4] = {};
  for (int k0 = 0; k0 < Kdim; k0 += 32) {
    size_t aoff0 = (size_t)(mbase + srow) * Kdim + k0 + sseg;
    size_t aoff1 = aoff0 + (size_t)64 * Kdim;
    size_t boff0 = (size_t)(nbase + srow) * Kdim + k0 + sseg;
    size_t boff1 = boff0 + (size_t)64 * Kdim;
    f16x8 vah0 = *(const f16x8*)(Ah + aoff0);
    f16x8 vah1 = *(const f16x8*)(Ah + aoff1);
    f16x8 val0 = *(const f16x8*)(Al + aoff0);
    f16x8 val1 = *(const f16x8*)(Al + aoff1);
    f16x8 vbh0 = *(const f16x8*)(Bh + boff0);
    f16x8 vbh1 = *(const f16x8*)(Bh + boff1);
    f16x8 vbl0 = *(const f16x8*)(Bl + boff0);
    f16x8 vbl1 = *(const f16x8*)(Bl + boff1);
    __syncthreads();
    *(f16x8*)&Ash[srow][sseg] = vah0;  *(f16x8*)&Ash[srow + 64][sseg] = vah1;
    *(f16x8*)&Asl[srow][sseg] = val0;  *(f16x8*)&Asl[srow + 64][sseg] = val1;
    *(f16x8*)&Bsh[srow][sseg] = vbh0;  *(f16x8*)&Bsh[srow + 64][sseg] = vbh1;
    *(f16x8*)&Bsl[srow][sseg] = vbl0;  *(f16x8*)&Bsl[srow + 64][sseg] = vbl1;
    __syncthreads();
    f16x8 afh[4], afl[4];
#pragma unroll
    for (int i = 0; i < 4; ++i) {
      afh[i] = *(const f16x8*)&Ash[wr + i * 16 + fr][fk];
      afl[i] = *(const f16x8*)&Asl[wr + i * 16 + fr][fk];
    }
#pragma unroll
    for (int nc = 0; nc < 4; ++nc) {
      f16x8 bh8 = *(const f16x8*)&Bsh[wc + nc * 16 + fr][fk];
      f16x8 bl8 = *(const f16x8*)&Bsl[wc + nc * 16 + fr][fk];
#pragma unroll
      for (int i = 0; i < 4; ++i)
        acc[i][nc] = __builtin_amdgcn_mfma_f32_16x16x32_f16(afh[i], bh8, acc[i][nc], 0, 0, 0);
#pragma unroll
      for (int i = 0; i < 4; ++i)
        acc[i][nc] = __builtin_amdgcn_mfma_f32_16x16x32_f16(afl[i], bh8, acc[i][nc], 0, 0, 0);
#pragma unroll
      for (int i = 0; i < 4; ++i)
        acc[i][nc] = __builtin_amdgcn_mfma_f32_16x16x32_f16(afh[i], bl8, acc[i][nc], 0, 0, 0);
    }
  }
  // epilogue: C/D mapping col = lane&15, row = (lane>>4)*4 + reg
  int rbase = mbase + wr + ((lane >> 4) << 2);
#pragma unroll
  for (int i = 0; i < 4; ++i) {
#pragma unroll
    for (int nc = 0; nc < 4; ++nc) {
      int n = nbase + wc + nc * 16 + fr;
#pragma unroll
      for (int j = 0; j < 4; ++j) {
        int m = rbase + i * 16 + j;
        float c = acc[i][nc][j];
        if (EPI == 1) c += X[(size_t)m * Ndim + n] + bias[n];
        C[(size_t)m * Ndim + n] = c;
      }
    }
  }
}

// ---------------- Batched mm (16 batches): C = acoef*(A@B) + ecoef*E ----
// A [bh][256][256], B [bh][256][Ndim], C/E [bh][256][Ndim]. K fixed = 256.
__global__ __launch_bounds__(256) void bmm_kernel(
    const float* __restrict__ A, const float* __restrict__ B,
    float* __restrict__ C, int Ndim,
    const float* __restrict__ E, float ecoef, float acoef) {
  int bh = blockIdx.z;
  const float* Ab = A + ((size_t)bh << 16);
  const float* Bb = B + (size_t)bh * 256 * Ndim;
  float* Cb = C + (size_t)bh * 256 * Ndim;
  const float* Eb = E ? (E + (size_t)bh * 256 * Ndim) : nullptr;
  __shared__ float As[16][64];
  __shared__ float Bs[16][64];
  int tid = threadIdx.x;
  int tx = tid & 15, ty = tid >> 4;
  int mbase = blockIdx.y << 6, nbase = blockIdx.x << 6;
  int lr = tid >> 2, lc = tid & 3;
  int bk = tid >> 6, bn = tid & 63;
  float acc[4][4] = {};
  for (int k0 = 0; k0 < 256; k0 += 16) {
    float4 av = *(const float4*)(Ab + (size_t)(mbase + lr) * 256 + k0 + lc * 4);
    float b0 = Bb[(size_t)(k0 + bk) * Ndim + nbase + bn];
    float b1 = Bb[(size_t)(k0 + bk + 4) * Ndim + nbase + bn];
    float b2 = Bb[(size_t)(k0 + bk + 8) * Ndim + nbase + bn];
    float b3 = Bb[(size_t)(k0 + bk + 12) * Ndim + nbase + bn];
    __syncthreads();
    As[lc * 4 + 0][lr] = av.x; As[lc * 4 + 1][lr] = av.y;
    As[lc * 4 + 2][lr] = av.z; As[lc * 4 + 3][lr] = av.w;
    Bs[bk][bn] = b0; Bs[bk + 4][bn] = b1;
    Bs[bk + 8][bn] = b2; Bs[bk + 12][bn] = b3;
    __syncthreads();
#pragma unroll
    for (int kk = 0; kk < 16; ++kk) {
      float4 a4 = *(const float4*)&As[kk][ty * 4];
      float4 b4 = *(const float4*)&Bs[kk][tx * 4];
      acc[0][0] += a4.x * b4.x; acc[0][1] += a4.x * b4.y;
      acc[0][2] += a4.x * b4.z; acc[0][3] += a4.x * b4.w;
      acc[1][0] += a4.y * b4.x; acc[1][1] += a4.y * b4.y;
      acc[1][2] += a4.y * b4.z; acc[1][3] += a4.y * b4.w;
      acc[2][0] += a4.z * b4.x; acc[2][1] += a4.z * b4.y;
      acc[2][2] += a4.z * b4.z; acc[2][3] += a4.z * b4.w;
      acc[3][0] += a4.w * b4.x; acc[3][1] += a4.w * b4.y;
      acc[3][2] += a4.w * b4.z; acc[3][3] += a4.w * b4.w;
    }
  }
#pragma unroll
  for (int i = 0; i < 4; ++i) {
    int m = mbase + ty * 4 + i;
#pragma unroll
    for (int j = 0; j < 4; ++j) {
      int n = nbase + tx * 4 + j;
      float c = acoef * acc[i][j];
      if (Eb) c += ecoef * Eb[(size_t)m * Ndim + n];
      Cb[(size_t)m * Ndim + n] = c;
    }
  }
}

// ---------------- landmark mean pooling (q scaled) ----------------
__global__ __launch_bounds__(64) void landmarks_kernel(const float* __restrict__ qkv,
    float* __restrict__ ql, float* __restrict__ kl) {
  int blk = blockIdx.x;          // bh*256 + m
  int m = blk & 255, bh = blk >> 8;
  int b = bh >> 3, h = bh & 7;
  int d = threadIdx.x;
  const float* base = qkv + (size_t)(b * NSEQ + m * 32) * QLD + h * 64 + d;
  float sq = 0.f, sk = 0.f;
#pragma unroll 8
  for (int i = 0; i < 32; ++i) {
    sq += base[(size_t)i * QLD];
    sk += base[(size_t)i * QLD + 512];
  }
  ql[((size_t)bh * 256 + m) * 64 + d] = sq * (0.03125f * SCALEQ);
  kl[((size_t)bh * 256 + m) * 64 + d] = sk * 0.03125f;
}

// ---------------- attn2 = softmax(q_l @ k_l^T) [bh][256][256] ----------
__global__ __launch_bounds__(256) void attn2_kernel(const float* __restrict__ ql,
    const float* __restrict__ kl, float* __restrict__ a) {
  int bh = blockIdx.y;
  int rbase = blockIdx.x << 5;   // 32 rows
  __shared__ float qs[32][68];
  __shared__ float kst[64][68];  // transposed [d][j]
  __shared__ float sall[32][260];
  int tid = threadIdx.x;
  int r = tid >> 3, g = tid & 7;
  {
    const float* src = ql + ((size_t)bh * 256 + rbase + r) * 64 + g * 8;
    *(float4*)&qs[r][g * 8] = *(const float4*)src;
    *(float4*)&qs[r][g * 8 + 4] = *(const float4*)(src + 4);
  }
  int jl = tid >> 2, i0 = (tid & 3) << 4;
  for (int mc = 0; mc < 4; ++mc) {
    __syncthreads();
    {
      const float* src = kl + ((size_t)bh * 256 + mc * 64 + jl) * 64 + i0;
      float4 k0 = *(const float4*)src;
      float4 k1 = *(const float4*)(src + 4);
      float4 k2 = *(const float4*)(src + 8);
      float4 k3 = *(const float4*)(src + 12);
      TRWR(kst, i0, jl, k0, k1, k2, k3)
    }
    __syncthreads();
    float s0 = 0, s1 = 0, s2 = 0, s3 = 0, s4 = 0, s5 = 0, s6 = 0, s7 = 0;
#pragma unroll 8
    for (int d = 0; d < 64; ++d) {
      float qv = qs[r][d];
      float4 ka = *(const float4*)&kst[d][g * 8];
      float4 kb = *(const float4*)&kst[d][g * 8 + 4];
      s0 += qv * ka.x; s1 += qv * ka.y; s2 += qv * ka.z; s3 += qv * ka.w;
      s4 += qv * kb.x; s5 += qv * kb.y; s6 += qv * kb.z; s7 += qv * kb.w;
    }
    float* dstp = &sall[r][mc * 64 + g * 8];
    dstp[0] = s0; dstp[1] = s1; dstp[2] = s2; dstp[3] = s3;
    dstp[4] = s4; dstp[5] = s5; dstp[6] = s6; dstp[7] = s7;
  }
  __syncthreads();
  float mx = -3.0e38f;
#pragma unroll
  for (int k = 0; k < 32; ++k) mx = fmaxf(mx, sall[r][g + (k << 3)]);
  mx = fmaxf(mx, __shfl_xor(mx, 1));
  mx = fmaxf(mx, __shfl_xor(mx, 2));
  mx = fmaxf(mx, __shfl_xor(mx, 4));
  float sum = 0.f;
#pragma unroll
  for (int k = 0; k < 32; ++k) {
    float p = expf(sall[r][g + (k << 3)] - mx);
    sall[r][g + (k << 3)] = p;
    sum += p;
  }
  sum += __shfl_xor(sum, 1);
  sum += __shfl_xor(sum, 2);
  sum += __shfl_xor(sum, 4);
  float inv = 1.0f / sum;
  float* dst = a + ((size_t)bh * 256 + rbase + r) * 256;
#pragma unroll
  for (int k = 0; k < 32; ++k) dst[g + (k << 3)] = sall[r][g + (k << 3)] * inv;
}

// ---------------- pinv scale = max(rowsum)*max(colsum) ----------------
__global__ void scale_init(unsigned* sbuf) {
  if (threadIdx.x < 2) sbuf[threadIdx.x] = 0u;
}

__global__ __launch_bounds__(256) void scale_reduce(const float* __restrict__ a,
    unsigned* __restrict__ sbuf) {
  int bh = blockIdx.x;
  int tid = threadIdx.x;
  const float* ab = a + ((size_t)bh << 16);
  const float* row = ab + (size_t)tid * 256;
  float rs = 0.f;
  for (int j = 0; j < 256; ++j) rs += fabsf(row[j]);
  float cs = 0.f;
  for (int i = 0; i < 256; ++i) cs += fabsf(ab[((size_t)i << 8) + tid]);
#pragma unroll
  for (int o = 32; o > 0; o >>= 1) {
    rs = fmaxf(rs, __shfl_xor(rs, o));
    cs = fmaxf(cs, __shfl_xor(cs, o));
  }
  __shared__ float redr[4], redc[4];
  int w = tid >> 6;
  if ((tid & 63) == 0) { redr[w] = rs; redc[w] = cs; }
  __syncthreads();
  if (tid == 0) {
    float mr = fmaxf(fmaxf(redr[0], redr[1]), fmaxf(redr[2], redr[3]));
    float mc = fmaxf(fmaxf(redc[0], redc[1]), fmaxf(redc[2], redc[3]));
    atomicMax(sbuf + 0, __float_as_uint(mr));
    atomicMax(sbuf + 1, __float_as_uint(mc));
  }
}

__global__ __launch_bounds__(256) void z0_kernel(const float* __restrict__ a,
    const unsigned* __restrict__ sbuf, float* __restrict__ z) {
  float inv = 1.0f / (__uint_as_float(sbuf[0]) * __uint_as_float(sbuf[1]));
  size_t idx = (size_t)blockIdx.x * 256 + threadIdx.x;
  int bh = (int)(idx >> 16);
  int rem = (int)(idx & 65535);
  int i = rem >> 8, j = rem & 255;
  z[idx] = a[((size_t)bh << 16) + ((size_t)j << 8) + i] * inv;
}

// ---------------- kv = softmax(q_l @ k^T) @ v   (flash, split-n x4) ----
__global__ __launch_bounds__(256) void kv_flash(const float* __restrict__ ql,
    const float* __restrict__ qkv, float* __restrict__ po,
    float* __restrict__ pm, float* __restrict__ pl) {
  int sp = blockIdx.x;           // 4 splits of 2048
  int mt = blockIdx.y;           // 16 tiles of 16 rows
  int bh = blockIdx.z;           // 16
  int b = bh >> 3, h = bh & 7;
  __shared__ float qs[16][68];
  __shared__ float kst[64][68];  // transposed [d][j]
  __shared__ float vs[64][68];   // row-major [j][d]
  __shared__ float ps[16][68];
  int tid = threadIdx.x;
  int r = tid >> 4, g = tid & 15;
  {
    const float* src = ql + ((size_t)bh * 256 + mt * 16 + r) * 64 + g * 4;
    *(float4*)&qs[r][g * 4] = *(const float4*)src;
  }
  const float* kbase = qkv + (size_t)b * NSEQ * QLD + 512 + h * 64;
  const float* vbase = kbase + 512;
  float m_run = -3.0e38f, l_run = 0.f;
  float o0 = 0.f, o1 = 0.f, o2 = 0.f, o3 = 0.f;
  int d0 = g * 4;
  int jl = tid >> 2, i0 = (tid & 3) << 4;
  for (int c0 = sp * 2048; c0 < sp * 2048 + 2048; c0 += 64) {
    __syncthreads();
    {
      const float* ksrc = kbase + (size_t)(c0 + jl) * QLD + i0;
      const float* vsrc = vbase + (size_t)(c0 + jl) * QLD + i0;
      float4 k0 = *(const float4*)ksrc;
      float4 k1 = *(const float4*)(ksrc + 4);
      float4 k2 = *(const float4*)(ksrc + 8);
      float4 k3 = *(const float4*)(ksrc + 12);
      TRWR(kst, i0, jl, k0, k1, k2, k3)
      *(float4*)&vs[jl][i0 + 0]  = *(const float4*)vsrc;
      *(float4*)&vs[jl][i0 + 4]  = *(const float4*)(vsrc + 4);
      *(float4*)&vs[jl][i0 + 8]  = *(const float4*)(vsrc + 8);
      *(float4*)&vs[jl][i0 + 12] = *(const float4*)(vsrc + 12);
    }
    __syncthreads();
    float s0 = 0, s1 = 0, s2 = 0, s3 = 0;
#pragma unroll 8
    for (int d = 0; d < 64; ++d) {
      float qv = qs[r][d];
      float4 k4 = *(const float4*)&kst[d][g * 4];
      s0 += qv * k4.x; s1 += qv * k4.y; s2 += qv * k4.z; s3 += qv * k4.w;
    }
    float mx = fmaxf(fmaxf(s0, s1), fmaxf(s2, s3));
    mx = fmaxf(mx, __shfl_xor(mx, 1));
    mx = fmaxf(mx, __shfl_xor(mx, 2));
    mx = fmaxf(mx, __shfl_xor(mx, 4));
    mx = fmaxf(mx, __shfl_xor(mx, 8));
    float mnew = fmaxf(m_run, mx);
    float p0 = expf(s0 - mnew), p1 = expf(s1 - mnew);
    float p2 = expf(s2 - mnew), p3 = expf(s3 - mnew);
    float psum = p0 + p1 + p2 + p3;
    psum += __shfl_xor(psum, 1);
    psum += __shfl_xor(psum, 2);
    psum += __shfl_xor(psum, 4);
    psum += __shfl_xor(psum, 8);
    float corr = expf(m_run - mnew);
    l_run = l_run * corr + psum;
    m_run = mnew;
    float4 pw; pw.x = p0; pw.y = p1; pw.z = p2; pw.w = p3;
    *(float4*)&ps[r][g * 4] = pw;
    __syncthreads();
    o0 *= corr; o1 *= corr; o2 *= corr; o3 *= corr;
#pragma unroll 8
    for (int j = 0; j < 64; ++j) {
      float p = ps[r][j];
      float4 v4 = *(const float4*)&vs[j][d0];
      o0 += p * v4.x; o1 += p * v4.y; o2 += p * v4.z; o3 += p * v4.w;
    }
  }
  size_t rowi = ((size_t)sp * 16 + bh) * 256 + mt * 16 + r;
  float4 ow; ow.x = o0; ow.y = o1; ow.z = o2; ow.w = o3;
  *(float4*)&po[rowi * 64 + d0] = ow;
  if (g == 0) { pm[rowi] = m_run; pl[rowi] = l_run; }
}

__global__ __launch_bounds__(64) void kv_combine(const float* __restrict__ po,
    const float* __restrict__ pm, const float* __restrict__ pl,
    float* __restrict__ kv) {
  int row = blockIdx.x;          // bh*256 + m  (4096)
  int d = threadIdx.x;
  float m0 = pm[row], m1 = pm[4096 + row], m2 = pm[8192 + row], m3 = pm[12288 + row];
  float mg = fmaxf(fmaxf(m0, m1), fmaxf(m2, m3));
  float w0 = expf(m0 - mg), w1 = expf(m1 - mg), w2 = expf(m2 - mg), w3 = expf(m3 - mg);
  float l = pl[row] * w0 + pl[4096 + row] * w1 + pl[8192 + row] * w2 + pl[12288 + row] * w3;
  float o = po[(size_t)row * 64 + d] * w0
          + po[(size_t)(4096 + row) * 64 + d] * w1
          + po[(size_t)(8192 + row) * 64 + d] * w2
          + po[(size_t)(12288 + row) * 64 + d] * w3;
  kv[(size_t)row * 64 + d] = o / l;
}

// ---------------- depthwise residual conv (kernel 33 over seq) ---------
__global__ __launch_bounds__(256) void conv_kernel(const float* __restrict__ qkv,
    const float* __restrict__ w_res, float* __restrict__ outh) {
  int nt = blockIdx.x;           // 128 tiles of 64 rows
  int bh = blockIdx.y;           // 16
  int b = bh >> 3, h = bh & 7;
  __shared__ float vsh[96][64];
  __shared__ float wsh[33];
  int tid = threadIdx.x;
  if (tid < 33) wsh[tid] = w_res[h * 33 + tid];
  int nbase = nt << 6;
  const float* vb = qkv + (size_t)b * NSEQ * QLD + 1024 + h * 64;
  for (int i = tid; i < 96 * 16; i += 256) {
    int rr = i >> 4, c4 = (i & 15) << 2;
    int n = nbase - 16 + rr;
    float4 val;
    if (n >= 0 && n < NSEQ) val = *(const float4*)(vb + (size_t)n * QLD + c4);
    else { val.x = 0.f; val.y = 0.f; val.z = 0.f; val.w = 0.f; }
    *(float4*)&vsh[rr][c4] = val;
  }
  __syncthreads();
  int d = tid & 63;
  int r0 = tid >> 6;
  for (int r = r0; r < 64; r += 4) {
    float acc = 0.f;
#pragma unroll
    for (int k = 0; k < 33; ++k) acc += vsh[r + k][d] * wsh[k];
    outh[(size_t)(b * NSEQ + nbase + r) * 512 + h * 64 + d] = acc;
  }
}

// ---------------- out += softmax(q @ k_l^T) @ W  ------------------------
__global__ __launch_bounds__(256) void attn1_kernel(const float* __restrict__ qkv,
    const float* __restrict__ kl, const float* __restrict__ Wm,
    float* __restrict__ outh) {
  int bh = blockIdx.y;
  int b = bh >> 3, h = bh & 7;
  int rbase = blockIdx.x << 5;   // 32 rows of n
  __shared__ float qs[32][68];
  __shared__ float buf[64][68];  // k_l transposed for scores; W row-major for PV
  __shared__ float sall[32][260];
  int tid = threadIdx.x;
  int r = tid >> 3, g = tid & 7;
  {
    const float* src = qkv + (size_t)(b * NSEQ + rbase + r) * QLD + h * 64 + g * 8;
    float4 x0 = *(const float4*)src;
    float4 x1 = *(const float4*)(src + 4);
    x0.x *= SCALEQ; x0.y *= SCALEQ; x0.z *= SCALEQ; x0.w *= SCALEQ;
    x1.x *= SCALEQ; x1.y *= SCALEQ; x1.z *= SCALEQ; x1.w *= SCALEQ;
    *(float4*)&qs[r][g * 8] = x0;
    *(float4*)&qs[r][g * 8 + 4] = x1;
  }
  int jl = tid >> 2, i0 = (tid & 3) << 4;
  for (int mc = 0; mc < 4; ++mc) {
    __syncthreads();
    {
      const float* src = kl + ((size_t)bh * 256 + mc * 64 + jl) * 64 + i0;
      float4 k0 = *(const float4*)src;
      float4 k1 = *(const float4*)(src + 4);
      float4 k2 = *(const float4*)(src + 8);
      float4 k3 = *(const float4*)(src + 12);
      TRWR(buf, i0, jl, k0, k1, k2, k3)
    }
    __syncthreads();
    float s0 = 0, s1 = 0, s2 = 0, s3 = 0, s4 = 0, s5 = 0, s6 = 0, s7 = 0;
#pragma unroll 8
    for (int d = 0; d < 64; ++d) {
      float qv = qs[r][d];
      float4 ka = *(const float4*)&buf[d][g * 8];
      float4 kb = *(const float4*)&buf[d][g * 8 + 4];
      s0 += qv * ka.x; s1 += qv * ka.y; s2 += qv * ka.z; s3 += qv * ka.w;
      s4 += qv * kb.x; s5 += qv * kb.y; s6 += qv * kb.z; s7 += qv * kb.w;
    }
    float* dstp = &sall[r][mc * 64 + g * 8];
    dstp[0] = s0; dstp[1] = s1; dstp[2] = s2; dstp[3] = s3;
    dstp[4] = s4; dstp[5] = s5; dstp[6] = s6; dstp[7] = s7;
  }
  __syncthreads();
  float mx = -3.0e38f;
#pragma unroll
  for (int k = 0; k < 32; ++k) mx = fmaxf(mx, sall[r][g + (k << 3)]);
  mx = fmaxf(mx, __shfl_xor(mx, 1));
  mx = fmaxf(mx, __shfl_xor(mx, 2));
  mx = fmaxf(mx, __shfl_xor(mx, 4));
  float sum = 0.f;
#pragma unroll
  for (int k = 0; k < 32; ++k) {
    float p = expf(sall[r][g + (k << 3)] - mx);
    sall[r][g + (k << 3)] = p;
    sum += p;
  }
  sum += __shfl_xor(sum, 1);
  sum += __shfl_xor(sum, 2);
  sum += __shfl_xor(sum, 4);
  float inv = 1.0f / sum;
  float o0 = 0, o1 = 0, o2 = 0, o3 = 0, o4 = 0, o5 = 0, o6 = 0, o7 = 0;
  for (int mc = 0; mc < 4; ++mc) {
    __syncthreads();
    {
      const float* src = Wm + ((size_t)bh * 256 + mc * 64 + jl) * 64 + i0;
      *(float4*)&buf[jl][i0 + 0]  = *(const float4*)src;
      *(float4*)&buf[jl][i0 + 4]  = *(const float4*)(src + 4);
      *(float4*)&buf[jl][i0 + 8]  = *(const float4*)(src + 8);
      *(float4*)&buf[jl][i0 + 12] = *(const float4*)(src + 12);
    }
    __syncthreads();
#pragma unroll 8
    for (int j = 0; j < 64; ++j) {
      float p = sall[r][mc * 64 + j];
      float4 wa = *(const float4*)&buf[j][g * 8];
      float4 wb = *(const float4*)&buf[j][g * 8 + 4];
      o0 += p * wa.x; o1 += p * wa.y; o2 += p * wa.z; o3 += p * wa.w;
      o4 += p * wb.x; o5 += p * wb.y; o6 += p * wb.z; o7 += p * wb.w;
    }
  }
  float* dst = outh + (size_t)(b * NSEQ + rbase + r) * 512 + h * 64 + g * 8;
  float4 e0 = *(float4*)dst;
  float4 e1 = *(float4*)(dst + 4);
  e0.x += o0 * inv; e0.y += o1 * inv; e0.z += o2 * inv; e0.w += o3 * inv;
  e1.x += o4 * inv; e1.y += o5 * inv; e1.z += o6 * inv; e1.w += o7 * inv;
  *(float4*)dst = e0;
  *(float4*)(dst + 4) = e1;
}

// ======================================================================
extern "C" void kernel_launch(void* const* d_in, const int* in_sizes, int n_in,
                              void* d_out, int out_size, void* d_ws, size_t ws_size,
                              hipStream_t stream) {
  (void)in_sizes; (void)n_in; (void)out_size; (void)ws_size;
  const float* x     = (const float*)d_in[0];
  const float* gamma = (const float*)d_in[1];
  const float* beta  = (const float*)d_in[2];
  const float* w_qkv = (const float*)d_in[3];
  const float* w_out = (const float*)d_in[4];
  const float* b_out = (const float*)d_in[5];
  const float* w_res = (const float*)d_in[6];
  float* out = (float*)d_out;
  float* ws = (float*)d_ws;

  // ---- workspace layout (float units) ----
  float* qkv  = ws;                          // [0 .. 25,165,824)
  float* xreg = ws + 25165824;               // 8,388,608 multi-use region
  half_t* xh  = (half_t*)xreg;               // 8,388,608 halfs (dies after qkv gemm)
  half_t* xl  = (half_t*)(ws + 29360128);    // 8,388,608 halfs
  // pinv temporaries overlay xreg (xh/xl dead by then):
  float* A2 = xreg;
  float* Z0 = xreg + 1048576;
  float* Z1 = xreg + 2097152;
  float* AZ = xreg + 3145728;
  float* TT = xreg + 4194304;
  float* UU = xreg + 5242880;
  float* po = ws + 31457280;                 // 1,048,576 (kv_flash partials)
  float* pm = ws + 32505856;                 // 16,384
  float* pl = ws + 32522240;                 // 16,384
  // outh fp32 overlays the whole xreg (pinv temps + po/pm/pl dead by then):
  float* outh = xreg;                        // 8,388,608
  half_t* wq_h = (half_t*)(ws + 33554432);   // 786,432 halfs
  half_t* wq_l = (half_t*)(ws + 33947648);
  half_t* wo_h = (half_t*)(ws + 34340864);   // 262,144 halfs
  half_t* wo_l = (half_t*)(ws + 34471936);
  float* ql = ws + 34603008;                 // 262,144
  float* kl = ws + 34865152;                 // 262,144
  float* kv = ws + 35127296;                 // 262,144
  float* Wm = ws + 35389440;                 // 262,144
  unsigned* sbuf = (unsigned*)(ws + 35651584);
  // outh halfs overlay qkv (qkv dead after conv/attn1):
  half_t* oh_h = (half_t*)ws;                // 8,388,608 halfs
  half_t* oh_l = (half_t*)(ws + 4194304);

  ln_kernel<<<16384, 64, 0, stream>>>(x, gamma, beta, xh, xl);
  split_kernel<<<768, 256, 0, stream>>>(w_qkv, wq_h, wq_l, 196608);
  split_kernel<<<256, 256, 0, stream>>>(w_out, wo_h, wo_l, 65536);

  gemm_mfma<0><<<dim3(1536 / 128, 16384 / 128), 256, 0, stream>>>(
      xh, xl, wq_h, wq_l, qkv, 1536, 512, nullptr, nullptr);

  landmarks_kernel<<<4096, 64, 0, stream>>>(qkv, ql, kl);

  attn2_kernel<<<dim3(8, 16), 256, 0, stream>>>(ql, kl, A2);

  scale_init<<<1, 64, 0, stream>>>(sbuf);
  scale_reduce<<<16, 256, 0, stream>>>(A2, sbuf);
  z0_kernel<<<4096, 256, 0, stream>>>(A2, sbuf, Z0);

  float* zc = Z0;
  float* zn = Z1;
  for (int it = 0; it < 6; ++it) {
    dim3 gb(4, 4, 16);
    bmm_kernel<<<gb, 256, 0, stream>>>(A2, zc, AZ, 256, nullptr, 0.f, 1.f);
    bmm_kernel<<<gb, 256, 0, stream>>>(AZ, AZ, TT, 256, AZ, 7.f, -1.f);
    bmm_kernel<<<gb, 256, 0, stream>>>(AZ, TT, UU, 256, AZ, 15.f, -1.f);
    bmm_kernel<<<gb, 256, 0, stream>>>(zc, UU, zn, 256, zc, 3.25f, -0.25f);
    float* t = zc; zc = zn; zn = t;
  }

  kv_flash<<<dim3(4, 16, 16), 256, 0, stream>>>(ql, qkv, po, pm, pl);
  kv_combine<<<4096, 64, 0, stream>>>(po, pm, pl, kv);

  // W = pinv @ kv   [bh][256][64]
  bmm_kernel<<<dim3(1, 4, 16), 256, 0, stream>>>(zc, kv, Wm, 64, nullptr, 0.f, 1.f);

  conv_kernel<<<dim3(128, 16), 256, 0, stream>>>(qkv, w_res, outh);
  attn1_kernel<<<dim3(256, 16), 256, 0, stream>>>(qkv, kl, Wm, outh);

  split_kernel<<<8192, 256, 0, stream>>>(outh, oh_h, oh_l, 2097152);

  gemm_mfma<1><<<dim3(512 / 128, 16384 / 128), 256, 0, stream>>>(
      oh_h, oh_l, wo_h, wo_l, out, 512, 512, x, b_out);
}

// Round 10
// 954.505 us; speedup vs baseline: 1.4902x; 1.2551x over previous
//
#include <hip/hip_runtime.h>
#include <math.h>

// TransLayer (Nystrom attention) for MI355X.
// Split-fp16 MFMA for dense GEMMs + both flash attentions; fp32 pinv chain.
// Needs ws_size >= 142,606,344 bytes (35,651,586 floats).

#define NSEQ 8192
#define SCALEQ 0.125f   // 64^-0.5

typedef _Float16 half_t;
typedef __attribute__((ext_vector_type(8))) _Float16 f16x8;
typedef __attribute__((ext_vector_type(4))) _Float16 f16x4;
typedef __attribute__((ext_vector_type(4))) float f32x4;

#define TRWR(ARR, I0, J, V0, V1, V2, V3)                                   \
  ARR[(I0) + 0][J] = V0.x;  ARR[(I0) + 1][J] = V0.y;                       \
  ARR[(I0) + 2][J] = V0.z;  ARR[(I0) + 3][J] = V0.w;                       \
  ARR[(I0) + 4][J] = V1.x;  ARR[(I0) + 5][J] = V1.y;                       \
  ARR[(I0) + 6][J] = V1.z;  ARR[(I0) + 7][J] = V1.w;                       \
  ARR[(I0) + 8][J] = V2.x;  ARR[(I0) + 9][J] = V2.y;                       \
  ARR[(I0) +10][J] = V2.z;  ARR[(I0) +11][J] = V2.w;                       \
  ARR[(I0) +12][J] = V3.x;  ARR[(I0) +13][J] = V3.y;                       \
  ARR[(I0) +14][J] = V3.z;  ARR[(I0) +15][J] = V3.w;

// ---------------- LayerNorm: one wave per row; writes hi/lo fp16 -------
__global__ __launch_bounds__(64) void ln_kernel(const float* __restrict__ x,
    const float* __restrict__ gamma, const float* __restrict__ beta,
    half_t* __restrict__ xh, half_t* __restrict__ xl) {
  int row = blockIdx.x;
  int t = threadIdx.x;
  const float4* xr = (const float4*)(x + (size_t)row * 512);
  float4 v0 = xr[t];
  float4 v1 = xr[t + 64];
  float s = v0.x + v0.y + v0.z + v0.w + v1.x + v1.y + v1.z + v1.w;
#pragma unroll
  for (int o = 32; o > 0; o >>= 1) s += __shfl_xor(s, o);
  float mu = s * (1.0f / 512.0f);
  float d, q = 0.f;
  d = v0.x - mu; q += d * d;  d = v0.y - mu; q += d * d;
  d = v0.z - mu; q += d * d;  d = v0.w - mu; q += d * d;
  d = v1.x - mu; q += d * d;  d = v1.y - mu; q += d * d;
  d = v1.z - mu; q += d * d;  d = v1.w - mu; q += d * d;
#pragma unroll
  for (int o = 32; o > 0; o >>= 1) q += __shfl_xor(q, o);
  float inv = rsqrtf(q * (1.0f / 512.0f) + 1e-5f);
  const float4* gp = (const float4*)gamma;
  const float4* bp = (const float4*)beta;
  float4 g0 = gp[t], g1 = gp[t + 64], b0 = bp[t], b1 = bp[t + 64];
  float a[8];
  a[0] = (v0.x - mu) * inv * g0.x + b0.x;
  a[1] = (v0.y - mu) * inv * g0.y + b0.y;
  a[2] = (v0.z - mu) * inv * g0.z + b0.z;
  a[3] = (v0.w - mu) * inv * g0.w + b0.w;
  a[4] = (v1.x - mu) * inv * g1.x + b1.x;
  a[5] = (v1.y - mu) * inv * g1.y + b1.y;
  a[6] = (v1.z - mu) * inv * g1.z + b1.z;
  a[7] = (v1.w - mu) * inv * g1.w + b1.w;
  f16x4 h0, h1, l0, l1;
#pragma unroll
  for (int j = 0; j < 4; ++j) {
    h0[j] = (half_t)a[j];     l0[j] = (half_t)(a[j] - (float)h0[j]);
    h1[j] = (half_t)a[4 + j]; l1[j] = (half_t)(a[4 + j] - (float)h1[j]);
  }
  half_t* hp = xh + (size_t)row * 512 + t * 4;
  half_t* lp = xl + (size_t)row * 512 + t * 4;
  *(f16x4*)hp = h0; *(f16x4*)(hp + 256) = h1;
  *(f16x4*)lp = l0; *(f16x4*)(lp + 256) = l1;
}

// ---------------- fp32 -> (hi, lo) fp16 splitter -----------------------
__global__ __launch_bounds__(256) void split_kernel(const float* __restrict__ src,
    half_t* __restrict__ hi, half_t* __restrict__ lo, int n4) {
  int i = blockIdx.x * 256 + threadIdx.x;
  if (i >= n4) return;
  float4 v = ((const float4*)src)[i];
  f16x4 h, l;
  h[0] = (half_t)v.x; l[0] = (half_t)(v.x - (float)h[0]);
  h[1] = (half_t)v.y; l[1] = (half_t)(v.y - (float)h[1]);
  h[2] = (half_t)v.z; l[2] = (half_t)(v.z - (float)h[2]);
  h[3] = (half_t)v.w; l[3] = (half_t)(v.w - (float)h[3]);
  ((f16x4*)hi)[i] = h;
  ((f16x4*)lo)[i] = l;
}

// -------- qkv GEMM (split-fp16 MFMA): writes q fp32, K split, V^T split --
__global__ __launch_bounds__(256) void gemm_mfma_qkv(
    const half_t* __restrict__ Ah, const half_t* __restrict__ Al,
    const half_t* __restrict__ Bh, const half_t* __restrict__ Bl,
    int Kdim, float* __restrict__ qb,
    half_t* __restrict__ kh_, half_t* __restrict__ kl_,
    half_t* __restrict__ vth_, half_t* __restrict__ vtl_) {
  __shared__ half_t Ash[128][40];
  __shared__ half_t Asl[128][40];
  __shared__ half_t Bsh[128][40];
  __shared__ half_t Bsl[128][40];
  int tid = threadIdx.x;
  int lane = tid & 63;
  int wave = tid >> 6;
  int wr = (wave >> 1) << 6;
  int wc = (wave & 1) << 6;
  int mbase = blockIdx.y << 7, nbase = blockIdx.x << 7;
  int srow = tid >> 2;
  int sseg = (tid & 3) << 3;
  int fr = lane & 15;
  int fk = (lane >> 4) << 3;
  f32x4 acc[4][4] = {};
  for (int k0 = 0; k0 < Kdim; k0 += 32) {
    size_t aoff0 = (size_t)(mbase + srow) * Kdim + k0 + sseg;
    size_t aoff1 = aoff0 + (size_t)64 * Kdim;
    size_t boff0 = (size_t)(nbase + srow) * Kdim + k0 + sseg;
    size_t boff1 = boff0 + (size_t)64 * Kdim;
    f16x8 vah0 = *(const f16x8*)(Ah + aoff0);
    f16x8 vah1 = *(const f16x8*)(Ah + aoff1);
    f16x8 val0 = *(const f16x8*)(Al + aoff0);
    f16x8 val1 = *(const f16x8*)(Al + aoff1);
    f16x8 vbh0 = *(const f16x8*)(Bh + boff0);
    f16x8 vbh1 = *(const f16x8*)(Bh + boff1);
    f16x8 vbl0 = *(const f16x8*)(Bl + boff0);
    f16x8 vbl1 = *(const f16x8*)(Bl + boff1);
    __syncthreads();
    *(f16x8*)&Ash[srow][sseg] = vah0;  *(f16x8*)&Ash[srow + 64][sseg] = vah1;
    *(f16x8*)&Asl[srow][sseg] = val0;  *(f16x8*)&Asl[srow + 64][sseg] = val1;
    *(f16x8*)&Bsh[srow][sseg] = vbh0;  *(f16x8*)&Bsh[srow + 64][sseg] = vbh1;
    *(f16x8*)&Bsl[srow][sseg] = vbl0;  *(f16x8*)&Bsl[srow + 64][sseg] = vbl1;
    __syncthreads();
    f16x8 afh[4], afl[4];
#pragma unroll
    for (int i = 0; i < 4; ++i) {
      afh[i] = *(const f16x8*)&Ash[wr + i * 16 + fr][fk];
      afl[i] = *(const f16x8*)&Asl[wr + i * 16 + fr][fk];
    }
#pragma unroll
    for (int nc = 0; nc < 4; ++nc) {
      f16x8 bh8 = *(const f16x8*)&Bsh[wc + nc * 16 + fr][fk];
      f16x8 bl8 = *(const f16x8*)&Bsl[wc + nc * 16 + fr][fk];
#pragma unroll
      for (int i = 0; i < 4; ++i)
        acc[i][nc] = __builtin_amdgcn_mfma_f32_16x16x32_f16(afh[i], bh8, acc[i][nc], 0, 0, 0);
#pragma unroll
      for (int i = 0; i < 4; ++i)
        acc[i][nc] = __builtin_amdgcn_mfma_f32_16x16x32_f16(afl[i], bh8, acc[i][nc], 0, 0, 0);
#pragma unroll
      for (int i = 0; i < 4; ++i)
        acc[i][nc] = __builtin_amdgcn_mfma_f32_16x16x32_f16(afh[i], bl8, acc[i][nc], 0, 0, 0);
    }
  }
  // epilogue: C/D mapping col = lane&15, row = (lane>>4)*4 + reg
  int rbase = mbase + wr + ((lane >> 4) << 2);
#pragma unroll
  for (int i = 0; i < 4; ++i) {
#pragma unroll
    for (int nc = 0; nc < 4; ++nc) {
      int n = nbase + wc + nc * 16 + fr;
      int reg = n >> 9;              // 0:q 1:k 2:v (uniform per block: 128 | 512)
      int hh = (n & 511) >> 6, dd = n & 63;
#pragma unroll
      for (int j = 0; j < 4; ++j) {
        int m = rbase + i * 16 + j;
        float cv = acc[i][nc][j];
        if (reg == 0) {
          qb[(size_t)m * 512 + n] = cv;
        } else {
          int b = m >> 13, np = m & 8191;
          size_t bhd = (size_t)(b * 8 + hh);
          half_t hi = (half_t)cv;
          half_t lo = (half_t)(cv - (float)hi);
          if (reg == 1) {
            kh_[(bhd * 8192 + np) * 64 + dd] = hi;
            kl_[(bhd * 8192 + np) * 64 + dd] = lo;
          } else {
            vth_[(bhd * 64 + dd) * 8192 + np] = hi;
            vtl_[(bhd * 64 + dd) * 8192 + np] = lo;
          }
        }
      }
    }
  }
}

// -------- out GEMM (split-fp16 MFMA): C = A@B^T + X + bias -------------
__global__ __launch_bounds__(256) void gemm_mfma_out(
    const half_t* __restrict__ Ah, const half_t* __restrict__ Al,
    const half_t* __restrict__ Bh, const half_t* __restrict__ Bl,
    float* __restrict__ C, int Ndim, int Kdim,
    const float* __restrict__ X, const float* __restrict__ bias) {
  __shared__ half_t Ash[128][40];
  __shared__ half_t Asl[128][40];
  __shared__ half_t Bsh[128][40];
  __shared__ half_t Bsl[128][40];
  int tid = threadIdx.x;
  int lane = tid & 63;
  int wave = tid >> 6;
  int wr = (wave >> 1) << 6;
  int wc = (wave & 1) << 6;
  int mbase = blockIdx.y << 7, nbase = blockIdx.x << 7;
  int srow = tid >> 2;
  int sseg = (tid & 3) << 3;
  int fr = lane & 15;
  int fk = (lane >> 4) << 3;
  f32x4 acc[4][4] = {};
  for (int k0 = 0; k0 < Kdim; k0 += 32) {
    size_t aoff0 = (size_t)(mbase + srow) * Kdim + k0 + sseg;
    size_t aoff1 = aoff0 + (size_t)64 * Kdim;
    size_t boff0 = (size_t)(nbase + srow) * Kdim + k0 + sseg;
    size_t boff1 = boff0 + (size_t)64 * Kdim;
    f16x8 vah0 = *(const f16x8*)(Ah + aoff0);
    f16x8 vah1 = *(const f16x8*)(Ah + aoff1);
    f16x8 val0 = *(const f16x8*)(Al + aoff0);
    f16x8 val1 = *(const f16x8*)(Al + aoff1);
    f16x8 vbh0 = *(const f16x8*)(Bh + boff0);
    f16x8 vbh1 = *(const f16x8*)(Bh + boff1);
    f16x8 vbl0 = *(const f16x8*)(Bl + boff0);
    f16x8 vbl1 = *(const f16x8*)(Bl + boff1);
    __syncthreads();
    *(f16x8*)&Ash[srow][sseg] = vah0;  *(f16x8*)&Ash[srow + 64][sseg] = vah1;
    *(f16x8*)&Asl[srow][sseg] = val0;  *(f16x8*)&Asl[srow + 64][sseg] = val1;
    *(f16x8*)&Bsh[srow][sseg] = vbh0;  *(f16x8*)&Bsh[srow + 64][sseg] = vbh1;
    *(f16x8*)&Bsl[srow][sseg] = vbl0;  *(f16x8*)&Bsl[srow + 64][sseg] = vbl1;
    __syncthreads();
    f16x8 afh[4], afl[4];
#pragma unroll
    for (int i = 0; i < 4; ++i) {
      afh[i] = *(const f16x8*)&Ash[wr + i * 16 + fr][fk];
      afl[i] = *(const f16x8*)&Asl[wr + i * 16 + fr][fk];
    }
#pragma unroll
    for (int nc = 0; nc < 4; ++nc) {
      f16x8 bh8 = *(const f16x8*)&Bsh[wc + nc * 16 + fr][fk];
      f16x8 bl8 = *(const f16x8*)&Bsl[wc + nc * 16 + fr][fk];
#pragma unroll
      for (int i = 0; i < 4; ++i)
        acc[i][nc] = __builtin_amdgcn_mfma_f32_16x16x32_f16(afh[i], bh8, acc[i][nc], 0, 0, 0);
#pragma unroll
      for (int i = 0; i < 4; ++i)
        acc[i][nc] = __builtin_amdgcn_mfma_f32_16x16x32_f16(afl[i], bh8, acc[i][nc], 0, 0, 0);
#pragma unroll
      for (int i = 0; i < 4; ++i)
        acc[i][nc] = __builtin_amdgcn_mfma_f32_16x16x32_f16(afh[i], bl8, acc[i][nc], 0, 0, 0);
    }
  }
  int rbase = mbase + wr + ((lane >> 4) << 2);
#pragma unroll
  for (int i = 0; i < 4; ++i) {
#pragma unroll
    for (int nc = 0; nc < 4; ++nc) {
      int n = nbase + wc + nc * 16 + fr;
#pragma unroll
      for (int j = 0; j < 4; ++j) {
        int m = rbase + i * 16 + j;
        float c = acc[i][nc][j] + X[(size_t)m * Ndim + n] + bias[n];
        C[(size_t)m * Ndim + n] = c;
      }
    }
  }
}

// ---------------- Batched mm (fp32): C = acoef*(A@B) + ecoef*E ---------
__global__ __launch_bounds__(256) void bmm_kernel(
    const float* __restrict__ A, const float* __restrict__ B,
    float* __restrict__ C, int Ndim,
    const float* __restrict__ E, float ecoef, float acoef) {
  int bh = blockIdx.z;
  const float* Ab = A + ((size_t)bh << 16);
  const float* Bb = B + (size_t)bh * 256 * Ndim;
  float* Cb = C + (size_t)bh * 256 * Ndim;
  const float* Eb = E ? (E + (size_t)bh * 256 * Ndim) : nullptr;
  __shared__ float As[16][64];
  __shared__ float Bs[16][64];
  int tid = threadIdx.x;
  int tx = tid & 15, ty = tid >> 4;
  int mbase = blockIdx.y << 6, nbase = blockIdx.x << 6;
  int lr = tid >> 2, lc = tid & 3;
  int bk = tid >> 6, bn = tid & 63;
  float acc[4][4] = {};
  for (int k0 = 0; k0 < 256; k0 += 16) {
    float4 av = *(const float4*)(Ab + (size_t)(mbase + lr) * 256 + k0 + lc * 4);
    float b0 = Bb[(size_t)(k0 + bk) * Ndim + nbase + bn];
    float b1 = Bb[(size_t)(k0 + bk + 4) * Ndim + nbase + bn];
    float b2 = Bb[(size_t)(k0 + bk + 8) * Ndim + nbase + bn];
    float b3 = Bb[(size_t)(k0 + bk + 12) * Ndim + nbase + bn];
    __syncthreads();
    As[lc * 4 + 0][lr] = av.x; As[lc * 4 + 1][lr] = av.y;
    As[lc * 4 + 2][lr] = av.z; As[lc * 4 + 3][lr] = av.w;
    Bs[bk][bn] = b0; Bs[bk + 4][bn] = b1;
    Bs[bk + 8][bn] = b2; Bs[bk + 12][bn] = b3;
    __syncthreads();
#pragma unroll
    for (int kk = 0; kk < 16; ++kk) {
      float4 a4 = *(const float4*)&As[kk][ty * 4];
      float4 b4 = *(const float4*)&Bs[kk][tx * 4];
      acc[0][0] += a4.x * b4.x; acc[0][1] += a4.x * b4.y;
      acc[0][2] += a4.x * b4.z; acc[0][3] += a4.x * b4.w;
      acc[1][0] += a4.y * b4.x; acc[1][1] += a4.y * b4.y;
      acc[1][2] += a4.y * b4.z; acc[1][3] += a4.y * b4.w;
      acc[2][0] += a4.z * b4.x; acc[2][1] += a4.z * b4.y;
      acc[2][2] += a4.z * b4.z; acc[2][3] += a4.z * b4.w;
      acc[3][0] += a4.w * b4.x; acc[3][1] += a4.w * b4.y;
      acc[3][2] += a4.w * b4.z; acc[3][3] += a4.w * b4.w;
    }
  }
#pragma unroll
  for (int i = 0; i < 4; ++i) {
    int m = mbase + ty * 4 + i;
#pragma unroll
    for (int j = 0; j < 4; ++j) {
      int n = nbase + tx * 4 + j;
      float c = acoef * acc[i][j];
      if (Eb) c += ecoef * Eb[(size_t)m * Ndim + n];
      Cb[(size_t)m * Ndim + n] = c;
    }
  }
}

// ---------------- landmark mean pooling (q scaled) + fp16 splits -------
__global__ __launch_bounds__(64) void landmarks_kernel(
    const float* __restrict__ qb,
    const half_t* __restrict__ kh, const half_t* __restrict__ klo,
    float* __restrict__ ql, half_t* __restrict__ qlh, half_t* __restrict__ qll,
    float* __restrict__ klf, half_t* __restrict__ klh, half_t* __restrict__ kll) {
  int blk = blockIdx.x;          // bh*256 + m
  int mm = blk & 255, bh = blk >> 8;
  int b = bh >> 3, h = bh & 7;
  int d = threadIdx.x;
  const float* qbase = qb + ((size_t)(b * NSEQ + mm * 32)) * 512 + h * 64 + d;
  size_t kbase = ((size_t)bh * NSEQ + mm * 32) * 64 + d;
  float sq = 0.f, sk = 0.f;
#pragma unroll 8
  for (int i = 0; i < 32; ++i) {
    sq += qbase[(size_t)i * 512];
    sk += (float)kh[kbase + (size_t)i * 64] + (float)klo[kbase + (size_t)i * 64];
  }
  float qv = sq * (0.03125f * SCALEQ);
  float kvv = sk * 0.03125f;
  size_t o = ((size_t)bh * 256 + mm) * 64 + d;
  ql[o] = qv;
  klf[o] = kvv;
  half_t qhi = (half_t)qv;
  qlh[o] = qhi; qll[o] = (half_t)(qv - (float)qhi);
  half_t khi = (half_t)kvv;
  klh[o] = khi; kll[o] = (half_t)(kvv - (float)khi);
}

// ---------------- attn2 = softmax(q_l @ k_l^T) [bh][256][256] ----------
__global__ __launch_bounds__(256) void attn2_kernel(const float* __restrict__ ql,
    const float* __restrict__ kl, float* __restrict__ a) {
  int bh = blockIdx.y;
  int rbase = blockIdx.x << 5;   // 32 rows
  __shared__ float qs[32][68];
  __shared__ float kst[64][68];  // transposed [d][j]
  __shared__ float sall[32][260];
  int tid = threadIdx.x;
  int r = tid >> 3, g = tid & 7;
  {
    const float* src = ql + ((size_t)bh * 256 + rbase + r) * 64 + g * 8;
    *(float4*)&qs[r][g * 8] = *(const float4*)src;
    *(float4*)&qs[r][g * 8 + 4] = *(const float4*)(src + 4);
  }
  int jl = tid >> 2, i0 = (tid & 3) << 4;
  for (int mc = 0; mc < 4; ++mc) {
    __syncthreads();
    {
      const float* src = kl + ((size_t)bh * 256 + mc * 64 + jl) * 64 + i0;
      float4 k0 = *(const float4*)src;
      float4 k1 = *(const float4*)(src + 4);
      float4 k2 = *(const float4*)(src + 8);
      float4 k3 = *(const float4*)(src + 12);
      TRWR(kst, i0, jl, k0, k1, k2, k3)
    }
    __syncthreads();
    float s0 = 0, s1 = 0, s2 = 0, s3 = 0, s4 = 0, s5 = 0, s6 = 0, s7 = 0;
#pragma unroll 8
    for (int d = 0; d < 64; ++d) {
      float qv = qs[r][d];
      float4 ka = *(const float4*)&kst[d][g * 8];
      float4 kb = *(const float4*)&kst[d][g * 8 + 4];
      s0 += qv * ka.x; s1 += qv * ka.y; s2 += qv * ka.z; s3 += qv * ka.w;
      s4 += qv * kb.x; s5 += qv * kb.y; s6 += qv * kb.z; s7 += qv * kb.w;
    }
    float* dstp = &sall[r][mc * 64 + g * 8];
    dstp[0] = s0; dstp[1] = s1; dstp[2] = s2; dstp[3] = s3;
    dstp[4] = s4; dstp[5] = s5; dstp[6] = s6; dstp[7] = s7;
  }
  __syncthreads();
  float mx = -3.0e38f;
#pragma unroll
  for (int k = 0; k < 32; ++k) mx = fmaxf(mx, sall[r][g + (k << 3)]);
  mx = fmaxf(mx, __shfl_xor(mx, 1));
  mx = fmaxf(mx, __shfl_xor(mx, 2));
  mx = fmaxf(mx, __shfl_xor(mx, 4));
  float sum = 0.f;
#pragma unroll
  for (int k = 0; k < 32; ++k) {
    float p = expf(sall[r][g + (k << 3)] - mx);
    sall[r][g + (k << 3)] = p;
    sum += p;
  }
  sum += __shfl_xor(sum, 1);
  sum += __shfl_xor(sum, 2);
  sum += __shfl_xor(sum, 4);
  float inv = 1.0f / sum;
  float* dst = a + ((size_t)bh * 256 + rbase + r) * 256;
#pragma unroll
  for (int k = 0; k < 32; ++k) dst[g + (k << 3)] = sall[r][g + (k << 3)] * inv;
}

// ---------------- pinv scale = max(rowsum)*max(colsum) ----------------
__global__ void scale_init(unsigned* sbuf) {
  if (threadIdx.x < 2) sbuf[threadIdx.x] = 0u;
}

__global__ __launch_bounds__(256) void scale_reduce(const float* __restrict__ a,
    unsigned* __restrict__ sbuf) {
  int bh = blockIdx.x;
  int tid = threadIdx.x;
  const float* ab = a + ((size_t)bh << 16);
  const float* row = ab + (size_t)tid * 256;
  float rs = 0.f;
  for (int j = 0; j < 256; ++j) rs += fabsf(row[j]);
  float cs = 0.f;
  for (int i = 0; i < 256; ++i) cs += fabsf(ab[((size_t)i << 8) + tid]);
#pragma unroll
  for (int o = 32; o > 0; o >>= 1) {
    rs = fmaxf(rs, __shfl_xor(rs, o));
    cs = fmaxf(cs, __shfl_xor(cs, o));
  }
  __shared__ float redr[4], redc[4];
  int w = tid >> 6;
  if ((tid & 63) == 0) { redr[w] = rs; redc[w] = cs; }
  __syncthreads();
  if (tid == 0) {
    float mr = fmaxf(fmaxf(redr[0], redr[1]), fmaxf(redr[2], redr[3]));
    float mc = fmaxf(fmaxf(redc[0], redc[1]), fmaxf(redc[2], redc[3]));
    atomicMax(sbuf + 0, __float_as_uint(mr));
    atomicMax(sbuf + 1, __float_as_uint(mc));
  }
}

__global__ __launch_bounds__(256) void z0_kernel(const float* __restrict__ a,
    const unsigned* __restrict__ sbuf, float* __restrict__ z) {
  float inv = 1.0f / (__uint_as_float(sbuf[0]) * __uint_as_float(sbuf[1]));
  size_t idx = (size_t)blockIdx.x * 256 + threadIdx.x;
  int bh = (int)(idx >> 16);
  int rem = (int)(idx & 65535);
  int i = rem >> 8, j = rem & 255;
  z[idx] = a[((size_t)bh << 16) + ((size_t)j << 8) + i] * inv;
}

// ==== kv = softmax(q_l @ k^T) @ v  — MFMA flash, split-n x16 ===========
// S^T = mfma32(K, q^T): lane-local q-row (col=lane&15). PV via mfma16:
// P quads (D-layout of S^T) are directly the B-operand of 16x16x16.
__global__ __launch_bounds__(256) void kv_flash_mfma(
    const half_t* __restrict__ qlh, const half_t* __restrict__ qll,
    const half_t* __restrict__ kh, const half_t* __restrict__ klo,
    const half_t* __restrict__ vth, const half_t* __restrict__ vtl,
    float* __restrict__ po, float* __restrict__ pm, float* __restrict__ pl) {
  __shared__ __align__(16) half_t sKh[4096], sKl[4096], sVh[4096], sVl[4096];
  int sp = blockIdx.x;           // 16 splits of 512 keys
  int qt = blockIdx.y;           // 2 tiles of 128 q
  int bh = blockIdx.z;
  int tid = threadIdx.x;
  int lane = tid & 63, wave = tid >> 6;
  int l15 = lane & 15, lg = lane >> 4;
  int qbase = qt * 128 + wave * 32;
  f16x8 qh[2][2], qlo_[2][2];    // [qsub][ks]
#pragma unroll
  for (int qs = 0; qs < 2; ++qs)
#pragma unroll
    for (int ks = 0; ks < 2; ++ks) {
      size_t off = ((size_t)bh * 256 + qbase + qs * 16 + l15) * 64 + ks * 32 + lg * 8;
      qh[qs][ks] = *(const f16x8*)(qlh + off);
      qlo_[qs][ks] = *(const f16x8*)(qll + off);
    }
  float m_run[2] = {-3.0e38f, -3.0e38f};
  float l_run[2] = {0.f, 0.f};
  f32x4 acc[2][4] = {};
  int sr = tid & 63, sg = tid >> 6;
  int wA = sr * 64 + ((sg * 8) ^ ((sr & 7) << 3));
  int wB = sr * 64 + (((sg + 4) * 8) ^ ((sr & 7) << 3));
  for (int c = 0; c < 8; ++c) {
    int c0 = sp * 512 + c * 64;
    size_t kg = ((size_t)bh * NSEQ + c0 + sr) * 64 + sg * 8;
    size_t vg = ((size_t)bh * 64 + sr) * NSEQ + c0 + sg * 8;
    f16x8 rk0 = *(const f16x8*)(kh + kg);
    f16x8 rk1 = *(const f16x8*)(kh + kg + 32);
    f16x8 rk2 = *(const f16x8*)(klo + kg);
    f16x8 rk3 = *(const f16x8*)(klo + kg + 32);
    f16x8 rv0 = *(const f16x8*)(vth + vg);
    f16x8 rv1 = *(const f16x8*)(vth + vg + 32);
    f16x8 rv2 = *(const f16x8*)(vtl + vg);
    f16x8 rv3 = *(const f16x8*)(vtl + vg + 32);
    __syncthreads();
    *(f16x8*)&sKh[wA] = rk0; *(f16x8*)&sKh[wB] = rk1;
    *(f16x8*)&sKl[wA] = rk2; *(f16x8*)&sKl[wB] = rk3;
    *(f16x8*)&sVh[wA] = rv0; *(f16x8*)&sVh[wB] = rv1;
    *(f16x8*)&sVl[wA] = rv2; *(f16x8*)&sVl[wB] = rv3;
    __syncthreads();
    f32x4 s[2][4] = {};
#pragma unroll
    for (int ks = 0; ks < 2; ++ks) {
#pragma unroll
      for (int ns = 0; ns < 4; ++ns) {
        int r = ns * 16 + l15;
        int off = r * 64 + ((ks * 32 + lg * 8) ^ ((r & 7) << 3));
        f16x8 ah = *(const f16x8*)&sKh[off];
        f16x8 al = *(const f16x8*)&sKl[off];
#pragma unroll
        for (int qs = 0; qs < 2; ++qs) {
          s[qs][ns] = __builtin_amdgcn_mfma_f32_16x16x32_f16(ah, qh[qs][ks], s[qs][ns], 0, 0, 0);
          s[qs][ns] = __builtin_amdgcn_mfma_f32_16x16x32_f16(al, qh[qs][ks], s[qs][ns], 0, 0, 0);
          s[qs][ns] = __builtin_amdgcn_mfma_f32_16x16x32_f16(ah, qlo_[qs][ks], s[qs][ns], 0, 0, 0);
        }
      }
    }
#pragma unroll
    for (int qs = 0; qs < 2; ++qs) {
      float pmax = s[qs][0][0];
#pragma unroll
      for (int ns = 0; ns < 4; ++ns)
#pragma unroll
        for (int j = 0; j < 4; ++j) pmax = fmaxf(pmax, s[qs][ns][j]);
      pmax = fmaxf(pmax, __shfl_xor(pmax, 16));
      pmax = fmaxf(pmax, __shfl_xor(pmax, 32));
      float mnew = fmaxf(m_run[qs], pmax);
      float corr = expf(m_run[qs] - mnew);
      float psum = 0.f;
      f16x4 ph[4], plo_[4];
#pragma unroll
      for (int ns = 0; ns < 4; ++ns)
#pragma unroll
        for (int j = 0; j < 4; ++j) {
          float p = expf(s[qs][ns][j] - mnew);
          psum += p;
          half_t hi = (half_t)p;
          ph[ns][j] = hi;
          plo_[ns][j] = (half_t)(p - (float)hi);
        }
      psum += __shfl_xor(psum, 16);
      psum += __shfl_xor(psum, 32);
      l_run[qs] = l_run[qs] * corr + psum;
      m_run[qs] = mnew;
#pragma unroll
      for (int md = 0; md < 4; ++md) {
        acc[qs][md][0] *= corr; acc[qs][md][1] *= corr;
        acc[qs][md][2] *= corr; acc[qs][md][3] *= corr;
      }
#pragma unroll
      for (int nc = 0; nc < 4; ++nc)
#pragma unroll
        for (int md = 0; md < 4; ++md) {
          int r = md * 16 + l15;
          int off = r * 64 + ((nc * 16 + lg * 4) ^ ((r & 7) << 3));
          f16x4 vh = *(const f16x4*)&sVh[off];
          f16x4 vl = *(const f16x4*)&sVl[off];
          acc[qs][md] = __builtin_amdgcn_mfma_f32_16x16x16f16(vh, ph[nc], acc[qs][md], 0, 0, 0);
          acc[qs][md] = __builtin_amdgcn_mfma_f32_16x16x16f16(vl, ph[nc], acc[qs][md], 0, 0, 0);
          acc[qs][md] = __builtin_amdgcn_mfma_f32_16x16x16f16(vh, plo_[nc], acc[qs][md], 0, 0, 0);
        }
    }
  }
#pragma unroll
  for (int qs = 0; qs < 2; ++qs) {
    size_t row = (size_t)sp * 4096 + bh * 256 + qbase + qs * 16 + l15;
#pragma unroll
    for (int md = 0; md < 4; ++md) {
      float4 o;
      o.x = acc[qs][md][0]; o.y = acc[qs][md][1];
      o.z = acc[qs][md][2]; o.w = acc[qs][md][3];
      *(float4*)&po[row * 64 + md * 16 + lg * 4] = o;
    }
  }
  if (lg == 0) {
#pragma unroll
    for (int qs = 0; qs < 2; ++qs) {
      size_t row = (size_t)sp * 4096 + bh * 256 + qbase + qs * 16 + l15;
      pm[row] = m_run[qs];
      pl[row] = l_run[qs];
    }
  }
}

__global__ __launch_bounds__(64) void kv_combine16(const float* __restrict__ po,
    const float* __restrict__ pm, const float* __restrict__ pl,
    float* __restrict__ kv) {
  int row = blockIdx.x;          // bh*256 + m  (4096)
  int d = threadIdx.x;
  float mg = -3.0e38f;
#pragma unroll
  for (int j = 0; j < 16; ++j) mg = fmaxf(mg, pm[j * 4096 + row]);
  float l = 0.f, o = 0.f;
#pragma unroll
  for (int j = 0; j < 16; ++j) {
    float w = expf(pm[j * 4096 + row] - mg);
    l += pl[j * 4096 + row] * w;
    o += po[((size_t)(j * 4096 + row)) * 64 + d] * w;
  }
  kv[(size_t)row * 64 + d] = o / l;
}

// ---------------- Wm -> Wm^T hi/lo fp16 --------------------------------
__global__ __launch_bounds__(256) void wmsplit_kernel(const float* __restrict__ Wm,
    half_t* __restrict__ wth, half_t* __restrict__ wtl) {
  int idx = blockIdx.x * 256 + threadIdx.x;   // 262144
  int bh = idx >> 14, rem = idx & 16383;
  int m = rem >> 6, dd = rem & 63;
  float v = Wm[idx];
  half_t hi = (half_t)v;
  size_t o = ((size_t)bh * 64 + dd) * 256 + m;
  wth[o] = hi;
  wtl[o] = (half_t)(v - (float)hi);
}

// ---------------- depthwise residual conv (reads V^T splits) -----------
__global__ __launch_bounds__(256) void conv_kernel(
    const half_t* __restrict__ vth, const half_t* __restrict__ vtl,
    const float* __restrict__ w_res, float* __restrict__ outh) {
  int nt = blockIdx.x;           // 128 tiles of 64 rows
  int bh = blockIdx.y;           // 16
  int b = bh >> 3, h = bh & 7;
  __shared__ float vsh[64][97];
  __shared__ float wsh[33];
  int tid = threadIdx.x;
  if (tid < 33) wsh[tid] = w_res[h * 33 + tid];
  int nbase = nt << 6;
  {
    int d = tid >> 2, part = tid & 3;
    const half_t* vh = vth + ((size_t)bh * 64 + d) * NSEQ;
    const half_t* vl = vtl + ((size_t)bh * 64 + d) * NSEQ;
#pragma unroll
    for (int i8 = 0; i8 < 3; ++i8) {
      int colbase = part * 24 + i8 * 8;
      int n0 = nbase - 16 + colbase;
      if (n0 >= 0 && n0 + 8 <= NSEQ) {
        f16x8 a = *(const f16x8*)(vh + n0);
        f16x8 bb = *(const f16x8*)(vl + n0);
#pragma unroll
        for (int j = 0; j < 8; ++j) vsh[d][colbase + j] = (float)a[j] + (float)bb[j];
      } else {
#pragma unroll
        for (int j = 0; j < 8; ++j) {
          int n = n0 + j;
          vsh[d][colbase + j] = (n >= 0 && n < NSEQ)
              ? ((float)vh[n] + (float)vl[n]) : 0.f;
        }
      }
    }
  }
  __syncthreads();
  int d = tid & 63, rg = tid >> 6;
#pragma unroll
  for (int rr = 0; rr < 16; ++rr) {
    int r = rg * 16 + rr;
    float acc = 0.f;
#pragma unroll
    for (int k = 0; k < 33; ++k) acc += vsh[d][r + k] * wsh[k];
    outh[((size_t)(b * NSEQ + nbase + r)) * 512 + h * 64 + d] = acc;
  }
}

// ==== outh += softmax(q @ k_l^T) @ Wm — MFMA, same structure ===========
__global__ __launch_bounds__(256) void attn1_mfma(
    const float* __restrict__ qb,
    const half_t* __restrict__ klh, const half_t* __restrict__ kll,
    const half_t* __restrict__ wth, const half_t* __restrict__ wtl,
    float* __restrict__ outh) {
  __shared__ __align__(16) half_t sKh[4096], sKl[4096], sVh[4096], sVl[4096];
  int qt = blockIdx.x;           // 64 tiles of 128 q
  int bh = blockIdx.y;
  int b8 = (bh >> 3) * NSEQ;
  int h = bh & 7;
  int tid = threadIdx.x;
  int lane = tid & 63, wave = tid >> 6;
  int l15 = lane & 15, lg = lane >> 4;
  int qbase = qt * 128 + wave * 32;
  f16x8 qh[2][2], qlo_[2][2];
#pragma unroll
  for (int qs = 0; qs < 2; ++qs)
#pragma unroll
    for (int ks = 0; ks < 2; ++ks) {
      const float* src = qb + ((size_t)(b8 + qbase + qs * 16 + l15)) * 512
                       + h * 64 + ks * 32 + lg * 8;
      float4 f0 = *(const float4*)src;
      float4 f1 = *(const float4*)(src + 4);
      float v[8] = {f0.x, f0.y, f0.z, f0.w, f1.x, f1.y, f1.z, f1.w};
      f16x8 hh, ll;
#pragma unroll
      for (int j = 0; j < 8; ++j) {
        float sv = v[j] * SCALEQ;
        half_t hi = (half_t)sv;
        hh[j] = hi;
        ll[j] = (half_t)(sv - (float)hi);
      }
      qh[qs][ks] = hh;
      qlo_[qs][ks] = ll;
    }
  float m_run[2] = {-3.0e38f, -3.0e38f};
  float l_run[2] = {0.f, 0.f};
  f32x4 acc[2][4] = {};
  int sr = tid & 63, sg = tid >> 6;
  int wA = sr * 64 + ((sg * 8) ^ ((sr & 7) << 3));
  int wB = sr * 64 + (((sg + 4) * 8) ^ ((sr & 7) << 3));
  for (int c = 0; c < 4; ++c) {
    int c0 = c * 64;
    size_t kg = ((size_t)bh * 256 + c0 + sr) * 64 + sg * 8;
    size_t vg = ((size_t)bh * 64 + sr) * 256 + c0 + sg * 8;
    f16x8 rk0 = *(const f16x8*)(klh + kg);
    f16x8 rk1 = *(const f16x8*)(klh + kg + 32);
    f16x8 rk2 = *(const f16x8*)(kll + kg);
    f16x8 rk3 = *(const f16x8*)(kll + kg + 32);
    f16x8 rv0 = *(const f16x8*)(wth + vg);
    f16x8 rv1 = *(const f16x8*)(wth + vg + 32);
    f16x8 rv2 = *(const f16x8*)(wtl + vg);
    f16x8 rv3 = *(const f16x8*)(wtl + vg + 32);
    __syncthreads();
    *(f16x8*)&sKh[wA] = rk0; *(f16x8*)&sKh[wB] = rk1;
    *(f16x8*)&sKl[wA] = rk2; *(f16x8*)&sKl[wB] = rk3;
    *(f16x8*)&sVh[wA] = rv0; *(f16x8*)&sVh[wB] = rv1;
    *(f16x8*)&sVl[wA] = rv2; *(f16x8*)&sVl[wB] = rv3;
    __syncthreads();
    f32x4 s[2][4] = {};
#pragma unroll
    for (int ks = 0; ks < 2; ++ks) {
#pragma unroll
      for (int ns = 0; ns < 4; ++ns) {
        int r = ns * 16 + l15;
        int off = r * 64 + ((ks * 32 + lg * 8) ^ ((r & 7) << 3));
        f16x8 ah = *(const f16x8*)&sKh[off];
        f16x8 al = *(const f16x8*)&sKl[off];
#pragma unroll
        for (int qs = 0; qs < 2; ++qs) {
          s[qs][ns] = __builtin_amdgcn_mfma_f32_16x16x32_f16(ah, qh[qs][ks], s[qs][ns], 0, 0, 0);
          s[qs][ns] = __builtin_amdgcn_mfma_f32_16x16x32_f16(al, qh[qs][ks], s[qs][ns], 0, 0, 0);
          s[qs][ns] = __builtin_amdgcn_mfma_f32_16x16x32_f16(ah, qlo_[qs][ks], s[qs][ns], 0, 0, 0);
        }
      }
    }
#pragma unroll
    for (int qs = 0; qs < 2; ++qs) {
      float pmax = s[qs][0][0];
#pragma unroll
      for (int ns = 0; ns < 4; ++ns)
#pragma unroll
        for (int j = 0; j < 4; ++j) pmax = fmaxf(pmax, s[qs][ns][j]);
      pmax = fmaxf(pmax, __shfl_xor(pmax, 16));
      pmax = fmaxf(pmax, __shfl_xor(pmax, 32));
      float mnew = fmaxf(m_run[qs], pmax);
      float corr = expf(m_run[qs] - mnew);
      float psum = 0.f;
      f16x4 ph[4], plo_[4];
#pragma unroll
      for (int ns = 0; ns < 4; ++ns)
#pragma unroll
        for (int j = 0; j < 4; ++j) {
          float p = expf(s[qs][ns][j] - mnew);
          psum += p;
          half_t hi = (half_t)p;
          ph[ns][j] = hi;
          plo_[ns][j] = (half_t)(p - (float)hi);
        }
      psum += __shfl_xor(psum, 16);
      psum += __shfl_xor(psum, 32);
      l_run[qs] = l_run[qs] * corr + psum;
      m_run[qs] = mnew;
#pragma unroll
      for (int md = 0; md < 4; ++md) {
        acc[qs][md][0] *= corr; acc[qs][md][1] *= corr;
        acc[qs][md][2] *= corr; acc[qs][md][3] *= corr;
      }
#pragma unroll
      for (int nc = 0; nc < 4; ++nc)
#pragma unroll
        for (int md = 0; md < 4; ++md) {
          int r = md * 16 + l15;
          int off = r * 64 + ((nc * 16 + lg * 4) ^ ((r & 7) << 3));
          f16x4 vh = *(const f16x4*)&sVh[off];
          f16x4 vl = *(const f16x4*)&sVl[off];
          acc[qs][md] = __builtin_amdgcn_mfma_f32_16x16x16f16(vh, ph[nc], acc[qs][md], 0, 0, 0);
          acc[qs][md] = __builtin_amdgcn_mfma_f32_16x16x16f16(vl, ph[nc], acc[qs][md], 0, 0, 0);
          acc[qs][md] = __builtin_amdgcn_mfma_f32_16x16x16f16(vh, plo_[nc], acc[qs][md], 0, 0, 0);
        }
    }
  }
#pragma unroll
  for (int qs = 0; qs < 2; ++qs) {
    float linv = 1.0f / l_run[qs];
    size_t nrow = (size_t)(b8 + qbase + qs * 16 + l15);
#pragma unroll
    for (int md = 0; md < 4; ++md) {
      float* dst = outh + nrow * 512 + h * 64 + md * 16 + lg * 4;
      float4 e = *(float4*)dst;
      e.x += acc[qs][md][0] * linv;
      e.y += acc[qs][md][1] * linv;
      e.z += acc[qs][md][2] * linv;
      e.w += acc[qs][md][3] * linv;
      *(float4*)dst = e;
    }
  }
}

// ======================================================================
extern "C" void kernel_launch(void* const* d_in, const int* in_sizes, int n_in,
                              void* d_out, int out_size, void* d_ws, size_t ws_size,
                              hipStream_t stream) {
  (void)in_sizes; (void)n_in; (void)out_size; (void)ws_size;
  const float* x     = (const float*)d_in[0];
  const float* gamma = (const float*)d_in[1];
  const float* beta  = (const float*)d_in[2];
  const float* w_qkv = (const float*)d_in[3];
  const float* w_out = (const float*)d_in[4];
  const float* b_out = (const float*)d_in[5];
  const float* w_res = (const float*)d_in[6];
  float* out = (float*)d_out;
  float* ws = (float*)d_ws;

  // ---- workspace layout (float offsets) ----
  float* qb    = ws;                           // [0 .. 8,388,608) q fp32
  half_t* kh   = (half_t*)(ws + 8388608);      // K hi  [bh][8192][64]
  half_t* klo  = (half_t*)(ws + 12582912);     // K lo
  half_t* vth  = (half_t*)(ws + 16777216);     // V^T hi [bh][64][8192]
  half_t* vtl  = (half_t*)(ws + 20971520);     // V^T lo
  float* xreg  = ws + 25165824;                // 8.39M multi-use region
  half_t* xh   = (half_t*)xreg;                // ln out hi (dead after qkv gemm)
  half_t* xl   = (half_t*)(ws + 29360128);     // ln out lo
  float* A2    = xreg;                         // pinv temps overlay xreg
  float* Z0    = xreg + 1048576;
  float* Z1    = xreg + 2097152;
  float* AZ    = xreg + 3145728;
  float* TT    = xreg + 4194304;
  float* UU    = xreg + 5242880;
  float* po    = xreg + 2097152;               // overlays Z1..UU (dead post-pinv)
  float* pm    = xreg + 6291456;
  float* pl    = xreg + 6356992;
  half_t* qlh  = (half_t*)(xreg + 6422528);    // q_l hi/lo (dead before outh)
  half_t* qll  = (half_t*)(xreg + 6553600);
  float* outh  = xreg;                         // overlays all xreg post-Wm
  half_t* wq_h = (half_t*)(ws + 33554432);     // dead after qkv gemm
  half_t* wq_l = (half_t*)(ws + 33947648);     // dead after qkv gemm
  half_t* wo_h = (half_t*)(ws + 34340864);
  half_t* wo_l = (half_t*)(ws + 34471936);
  half_t* klh  = wq_h;                         // reuse wq_h region
  half_t* kll  = (half_t*)(ws + 33685504);
  half_t* wmt_h = wq_l;                        // reuse wq_l region
  half_t* wmt_l = (half_t*)(ws + 34078720);
  float* ql    = ws + 34603008;                // q_l fp32 (attn2)
  float* klf   = ws + 34865152;                // k_l fp32 (attn2)
  float* kv    = ws + 35127296;
  float* Wm    = ws + 35389440;
  unsigned* sbuf = (unsigned*)(ws + 35651584);
  half_t* oh_h = (half_t*)ws;                  // overlays qb (dead post-attn1)
  half_t* oh_l = (half_t*)(ws + 4194304);

  ln_kernel<<<16384, 64, 0, stream>>>(x, gamma, beta, xh, xl);
  split_kernel<<<768, 256, 0, stream>>>(w_qkv, wq_h, wq_l, 196608);
  split_kernel<<<256, 256, 0, stream>>>(w_out, wo_h, wo_l, 65536);

  gemm_mfma_qkv<<<dim3(12, 128), 256, 0, stream>>>(
      xh, xl, wq_h, wq_l, 512, qb, kh, klo, vth, vtl);

  landmarks_kernel<<<4096, 64, 0, stream>>>(qb, kh, klo, ql, qlh, qll, klf, klh, kll);

  attn2_kernel<<<dim3(8, 16), 256, 0, stream>>>(ql, klf, A2);

  scale_init<<<1, 64, 0, stream>>>(sbuf);
  scale_reduce<<<16, 256, 0, stream>>>(A2, sbuf);
  z0_kernel<<<4096, 256, 0, stream>>>(A2, sbuf, Z0);

  float* zc = Z0;
  float* zn = Z1;
  for (int it = 0; it < 6; ++it) {
    dim3 gb(4, 4, 16);
    bmm_kernel<<<gb, 256, 0, stream>>>(A2, zc, AZ, 256, nullptr, 0.f, 1.f);
    bmm_kernel<<<gb, 256, 0, stream>>>(AZ, AZ, TT, 256, AZ, 7.f, -1.f);
    bmm_kernel<<<gb, 256, 0, stream>>>(AZ, TT, UU, 256, AZ, 15.f, -1.f);
    bmm_kernel<<<gb, 256, 0, stream>>>(zc, UU, zn, 256, zc, 3.25f, -0.25f);
    float* t = zc; zc = zn; zn = t;
  }
  // zc == Z0 after 6 iterations

  kv_flash_mfma<<<dim3(16, 2, 16), 256, 0, stream>>>(
      qlh, qll, kh, klo, vth, vtl, po, pm, pl);
  kv_combine16<<<4096, 64, 0, stream>>>(po, pm, pl, kv);

  // W = pinv @ kv   [bh][256][64]
  bmm_kernel<<<dim3(1, 4, 16), 256, 0, stream>>>(zc, kv, Wm, 64, nullptr, 0.f, 1.f);
  wmsplit_kernel<<<1024, 256, 0, stream>>>(Wm, wmt_h, wmt_l);

  conv_kernel<<<dim3(128, 16), 256, 0, stream>>>(vth, vtl, w_res, outh);
  attn1_mfma<<<dim3(64, 16), 256, 0, stream>>>(qb, klh, kll, wmt_h, wmt_l, outh);

  split_kernel<<<8192, 256, 0, stream>>>(outh, oh_h, oh_l, 2097152);

  gemm_mfma_out<<<dim3(4, 128), 256, 0, stream>>>(
      oh_h, oh_l, wo_h, wo_l, out, 512, 512, x, b_out);
}

// Round 11
// 840.231 us; speedup vs baseline: 1.6929x; 1.1360x over previous
//
#include <hip/hip_runtime.h>
#include <math.h>

// TransLayer (Nystrom attention) for MI355X.
// Split-fp16 MFMA for dense GEMMs, both flash attentions, and the pinv
// Newton-Schulz chain. Needs ws_size >= 142,606,344 bytes.

#define NSEQ 8192
#define SCALEQ 0.125f   // 64^-0.5

typedef _Float16 half_t;
typedef __attribute__((ext_vector_type(8))) _Float16 f16x8;
typedef __attribute__((ext_vector_type(4))) _Float16 f16x4;
typedef __attribute__((ext_vector_type(4))) float f32x4;

#define TRWR(ARR, I0, J, V0, V1, V2, V3)                                   \
  ARR[(I0) + 0][J] = V0.x;  ARR[(I0) + 1][J] = V0.y;                       \
  ARR[(I0) + 2][J] = V0.z;  ARR[(I0) + 3][J] = V0.w;                       \
  ARR[(I0) + 4][J] = V1.x;  ARR[(I0) + 5][J] = V1.y;                       \
  ARR[(I0) + 6][J] = V1.z;  ARR[(I0) + 7][J] = V1.w;                       \
  ARR[(I0) + 8][J] = V2.x;  ARR[(I0) + 9][J] = V2.y;                       \
  ARR[(I0) +10][J] = V2.z;  ARR[(I0) +11][J] = V2.w;                       \
  ARR[(I0) +12][J] = V3.x;  ARR[(I0) +13][J] = V3.y;                       \
  ARR[(I0) +14][J] = V3.z;  ARR[(I0) +15][J] = V3.w;

// ---------------- LayerNorm: one wave per row; writes hi/lo fp16 -------
__global__ __launch_bounds__(64) void ln_kernel(const float* __restrict__ x,
    const float* __restrict__ gamma, const float* __restrict__ beta,
    half_t* __restrict__ xh, half_t* __restrict__ xl) {
  int row = blockIdx.x;
  int t = threadIdx.x;
  const float4* xr = (const float4*)(x + (size_t)row * 512);
  float4 v0 = xr[t];
  float4 v1 = xr[t + 64];
  float s = v0.x + v0.y + v0.z + v0.w + v1.x + v1.y + v1.z + v1.w;
#pragma unroll
  for (int o = 32; o > 0; o >>= 1) s += __shfl_xor(s, o);
  float mu = s * (1.0f / 512.0f);
  float d, q = 0.f;
  d = v0.x - mu; q += d * d;  d = v0.y - mu; q += d * d;
  d = v0.z - mu; q += d * d;  d = v0.w - mu; q += d * d;
  d = v1.x - mu; q += d * d;  d = v1.y - mu; q += d * d;
  d = v1.z - mu; q += d * d;  d = v1.w - mu; q += d * d;
#pragma unroll
  for (int o = 32; o > 0; o >>= 1) q += __shfl_xor(q, o);
  float inv = rsqrtf(q * (1.0f / 512.0f) + 1e-5f);
  const float4* gp = (const float4*)gamma;
  const float4* bp = (const float4*)beta;
  float4 g0 = gp[t], g1 = gp[t + 64], b0 = bp[t], b1 = bp[t + 64];
  float a[8];
  a[0] = (v0.x - mu) * inv * g0.x + b0.x;
  a[1] = (v0.y - mu) * inv * g0.y + b0.y;
  a[2] = (v0.z - mu) * inv * g0.z + b0.z;
  a[3] = (v0.w - mu) * inv * g0.w + b0.w;
  a[4] = (v1.x - mu) * inv * g1.x + b1.x;
  a[5] = (v1.y - mu) * inv * g1.y + b1.y;
  a[6] = (v1.z - mu) * inv * g1.z + b1.z;
  a[7] = (v1.w - mu) * inv * g1.w + b1.w;
  f16x4 h0, h1, l0, l1;
#pragma unroll
  for (int j = 0; j < 4; ++j) {
    h0[j] = (half_t)a[j];     l0[j] = (half_t)(a[j] - (float)h0[j]);
    h1[j] = (half_t)a[4 + j]; l1[j] = (half_t)(a[4 + j] - (float)h1[j]);
  }
  half_t* hp = xh + (size_t)row * 512 + t * 4;
  half_t* lp = xl + (size_t)row * 512 + t * 4;
  *(f16x4*)hp = h0; *(f16x4*)(hp + 256) = h1;
  *(f16x4*)lp = l0; *(f16x4*)(lp + 256) = l1;
}

// ---------------- fp32 -> (hi, lo) fp16 splitter -----------------------
__global__ __launch_bounds__(256) void split_kernel(const float* __restrict__ src,
    half_t* __restrict__ hi, half_t* __restrict__ lo, int n4) {
  int i = blockIdx.x * 256 + threadIdx.x;
  if (i >= n4) return;
  float4 v = ((const float4*)src)[i];
  f16x4 h, l;
  h[0] = (half_t)v.x; l[0] = (half_t)(v.x - (float)h[0]);
  h[1] = (half_t)v.y; l[1] = (half_t)(v.y - (float)h[1]);
  h[2] = (half_t)v.z; l[2] = (half_t)(v.z - (float)h[2]);
  h[3] = (half_t)v.w; l[3] = (half_t)(v.w - (float)h[3]);
  ((f16x4*)hi)[i] = h;
  ((f16x4*)lo)[i] = l;
}

// -------- qkv GEMM (split-fp16 MFMA): writes q fp32, K split, V^T split --
__global__ __launch_bounds__(256) void gemm_mfma_qkv(
    const half_t* __restrict__ Ah, const half_t* __restrict__ Al,
    const half_t* __restrict__ Bh, const half_t* __restrict__ Bl,
    int Kdim, float* __restrict__ qb,
    half_t* __restrict__ kh_, half_t* __restrict__ kl_,
    half_t* __restrict__ vth_, half_t* __restrict__ vtl_) {
  __shared__ half_t Ash[128][40];
  __shared__ half_t Asl[128][40];
  __shared__ half_t Bsh[128][40];
  __shared__ half_t Bsl[128][40];
  int tid = threadIdx.x;
  int lane = tid & 63;
  int wave = tid >> 6;
  int wr = (wave >> 1) << 6;
  int wc = (wave & 1) << 6;
  int mbase = blockIdx.y << 7, nbase = blockIdx.x << 7;
  int srow = tid >> 2;
  int sseg = (tid & 3) << 3;
  int fr = lane & 15;
  int fk = (lane >> 4) << 3;
  f32x4 acc[4][4] = {};
  for (int k0 = 0; k0 < Kdim; k0 += 32) {
    size_t aoff0 = (size_t)(mbase + srow) * Kdim + k0 + sseg;
    size_t aoff1 = aoff0 + (size_t)64 * Kdim;
    size_t boff0 = (size_t)(nbase + srow) * Kdim + k0 + sseg;
    size_t boff1 = boff0 + (size_t)64 * Kdim;
    f16x8 vah0 = *(const f16x8*)(Ah + aoff0);
    f16x8 vah1 = *(const f16x8*)(Ah + aoff1);
    f16x8 val0 = *(const f16x8*)(Al + aoff0);
    f16x8 val1 = *(const f16x8*)(Al + aoff1);
    f16x8 vbh0 = *(const f16x8*)(Bh + boff0);
    f16x8 vbh1 = *(const f16x8*)(Bh + boff1);
    f16x8 vbl0 = *(const f16x8*)(Bl + boff0);
    f16x8 vbl1 = *(const f16x8*)(Bl + boff1);
    __syncthreads();
    *(f16x8*)&Ash[srow][sseg] = vah0;  *(f16x8*)&Ash[srow + 64][sseg] = vah1;
    *(f16x8*)&Asl[srow][sseg] = val0;  *(f16x8*)&Asl[srow + 64][sseg] = val1;
    *(f16x8*)&Bsh[srow][sseg] = vbh0;  *(f16x8*)&Bsh[srow + 64][sseg] = vbh1;
    *(f16x8*)&Bsl[srow][sseg] = vbl0;  *(f16x8*)&Bsl[srow + 64][sseg] = vbl1;
    __syncthreads();
    f16x8 afh[4], afl[4];
#pragma unroll
    for (int i = 0; i < 4; ++i) {
      afh[i] = *(const f16x8*)&Ash[wr + i * 16 + fr][fk];
      afl[i] = *(const f16x8*)&Asl[wr + i * 16 + fr][fk];
    }
#pragma unroll
    for (int nc = 0; nc < 4; ++nc) {
      f16x8 bh8 = *(const f16x8*)&Bsh[wc + nc * 16 + fr][fk];
      f16x8 bl8 = *(const f16x8*)&Bsl[wc + nc * 16 + fr][fk];
#pragma unroll
      for (int i = 0; i < 4; ++i)
        acc[i][nc] = __builtin_amdgcn_mfma_f32_16x16x32_f16(afh[i], bh8, acc[i][nc], 0, 0, 0);
#pragma unroll
      for (int i = 0; i < 4; ++i)
        acc[i][nc] = __builtin_amdgcn_mfma_f32_16x16x32_f16(afl[i], bh8, acc[i][nc], 0, 0, 0);
#pragma unroll
      for (int i = 0; i < 4; ++i)
        acc[i][nc] = __builtin_amdgcn_mfma_f32_16x16x32_f16(afh[i], bl8, acc[i][nc], 0, 0, 0);
    }
  }
  // epilogue: C/D mapping col = lane&15, row = (lane>>4)*4 + reg
  int rbase = mbase + wr + ((lane >> 4) << 2);
#pragma unroll
  for (int i = 0; i < 4; ++i) {
#pragma unroll
    for (int nc = 0; nc < 4; ++nc) {
      int n = nbase + wc + nc * 16 + fr;
      int reg = n >> 9;              // 0:q 1:k 2:v (uniform per block: 128 | 512)
      int hh = (n & 511) >> 6, dd = n & 63;
#pragma unroll
      for (int j = 0; j < 4; ++j) {
        int m = rbase + i * 16 + j;
        float cv = acc[i][nc][j];
        if (reg == 0) {
          qb[(size_t)m * 512 + n] = cv;
        } else {
          int b = m >> 13, np = m & 8191;
          size_t bhd = (size_t)(b * 8 + hh);
          half_t hi = (half_t)cv;
          half_t lo = (half_t)(cv - (float)hi);
          if (reg == 1) {
            kh_[(bhd * 8192 + np) * 64 + dd] = hi;
            kl_[(bhd * 8192 + np) * 64 + dd] = lo;
          } else {
            vth_[(bhd * 64 + dd) * 8192 + np] = hi;
            vtl_[(bhd * 64 + dd) * 8192 + np] = lo;
          }
        }
      }
    }
  }
}

// -------- out GEMM (split-fp16 MFMA): C = A@B^T + X + bias -------------
__global__ __launch_bounds__(256) void gemm_mfma_out(
    const half_t* __restrict__ Ah, const half_t* __restrict__ Al,
    const half_t* __restrict__ Bh, const half_t* __restrict__ Bl,
    float* __restrict__ C, int Ndim, int Kdim,
    const float* __restrict__ X, const float* __restrict__ bias) {
  __shared__ half_t Ash[128][40];
  __shared__ half_t Asl[128][40];
  __shared__ half_t Bsh[128][40];
  __shared__ half_t Bsl[128][40];
  int tid = threadIdx.x;
  int lane = tid & 63;
  int wave = tid >> 6;
  int wr = (wave >> 1) << 6;
  int wc = (wave & 1) << 6;
  int mbase = blockIdx.y << 7, nbase = blockIdx.x << 7;
  int srow = tid >> 2;
  int sseg = (tid & 3) << 3;
  int fr = lane & 15;
  int fk = (lane >> 4) << 3;
  f32x4 acc[4][4] = {};
  for (int k0 = 0; k0 < Kdim; k0 += 32) {
    size_t aoff0 = (size_t)(mbase + srow) * Kdim + k0 + sseg;
    size_t aoff1 = aoff0 + (size_t)64 * Kdim;
    size_t boff0 = (size_t)(nbase + srow) * Kdim + k0 + sseg;
    size_t boff1 = boff0 + (size_t)64 * Kdim;
    f16x8 vah0 = *(const f16x8*)(Ah + aoff0);
    f16x8 vah1 = *(const f16x8*)(Ah + aoff1);
    f16x8 val0 = *(const f16x8*)(Al + aoff0);
    f16x8 val1 = *(const f16x8*)(Al + aoff1);
    f16x8 vbh0 = *(const f16x8*)(Bh + boff0);
    f16x8 vbh1 = *(const f16x8*)(Bh + boff1);
    f16x8 vbl0 = *(const f16x8*)(Bl + boff0);
    f16x8 vbl1 = *(const f16x8*)(Bl + boff1);
    __syncthreads();
    *(f16x8*)&Ash[srow][sseg] = vah0;  *(f16x8*)&Ash[srow + 64][sseg] = vah1;
    *(f16x8*)&Asl[srow][sseg] = val0;  *(f16x8*)&Asl[srow + 64][sseg] = val1;
    *(f16x8*)&Bsh[srow][sseg] = vbh0;  *(f16x8*)&Bsh[srow + 64][sseg] = vbh1;
    *(f16x8*)&Bsl[srow][sseg] = vbl0;  *(f16x8*)&Bsl[srow + 64][sseg] = vbl1;
    __syncthreads();
    f16x8 afh[4], afl[4];
#pragma unroll
    for (int i = 0; i < 4; ++i) {
      afh[i] = *(const f16x8*)&Ash[wr + i * 16 + fr][fk];
      afl[i] = *(const f16x8*)&Asl[wr + i * 16 + fr][fk];
    }
#pragma unroll
    for (int nc = 0; nc < 4; ++nc) {
      f16x8 bh8 = *(const f16x8*)&Bsh[wc + nc * 16 + fr][fk];
      f16x8 bl8 = *(const f16x8*)&Bsl[wc + nc * 16 + fr][fk];
#pragma unroll
      for (int i = 0; i < 4; ++i)
        acc[i][nc] = __builtin_amdgcn_mfma_f32_16x16x32_f16(afh[i], bh8, acc[i][nc], 0, 0, 0);
#pragma unroll
      for (int i = 0; i < 4; ++i)
        acc[i][nc] = __builtin_amdgcn_mfma_f32_16x16x32_f16(afl[i], bh8, acc[i][nc], 0, 0, 0);
#pragma unroll
      for (int i = 0; i < 4; ++i)
        acc[i][nc] = __builtin_amdgcn_mfma_f32_16x16x32_f16(afh[i], bl8, acc[i][nc], 0, 0, 0);
    }
  }
  int rbase = mbase + wr + ((lane >> 4) << 2);
#pragma unroll
  for (int i = 0; i < 4; ++i) {
#pragma unroll
    for (int nc = 0; nc < 4; ++nc) {
      int n = nbase + wc + nc * 16 + fr;
#pragma unroll
      for (int j = 0; j < 4; ++j) {
        int m = rbase + i * 16 + j;
        float c = acc[i][nc][j] + X[(size_t)m * Ndim + n] + bias[n];
        C[(size_t)m * Ndim + n] = c;
      }
    }
  }
}

// -------- Batched mm via split-fp16 MFMA: C = acoef*(A@B) + ecoef*E ----
// A,B,C,E fp32 [bh][256][256]. 64x64 tile, 4 waves (2x2), 2x2 frags, BK=32.
// B staged transposed into LDS [n][k] with bank-staggered scalar writes.
__global__ __launch_bounds__(256) void bmm_mfma(
    const float* __restrict__ A, const float* __restrict__ B,
    float* __restrict__ C,
    const float* __restrict__ E, float ecoef, float acoef) {
  __shared__ half_t Ash[64][40];
  __shared__ half_t Asl[64][40];
  __shared__ half_t Bsh[64][40];
  __shared__ half_t Bsl[64][40];
  int bh = blockIdx.z;
  const float* Ab = A + ((size_t)bh << 16);
  const float* Bb = B + ((size_t)bh << 16);
  float* Cb = C + ((size_t)bh << 16);
  const float* Eb = E ? (E + ((size_t)bh << 16)) : nullptr;
  int tid = threadIdx.x;
  int lane = tid & 63, wave = tid >> 6;
  int wr = (wave >> 1) << 5;    // 0/32
  int wc = (wave & 1) << 5;     // 0/32
  int mbase = blockIdx.y << 6, nbase = blockIdx.x << 6;
  int fr = lane & 15;
  int fk = (lane >> 4) << 3;
  int srA = tid >> 2, ssA = (tid & 3) << 3;    // A: row, k-seg
  int krB = tid >> 3;                          // B: k-row 0..31
  int g = tid & 7;                             // B: n-group
  int nsB = g << 3;                            // B: n-seg base
  f32x4 acc[2][2] = {};
  for (int k0 = 0; k0 < 256; k0 += 32) {
    const float* ap = Ab + (size_t)(mbase + srA) * 256 + k0 + ssA;
    float4 a0 = *(const float4*)ap;
    float4 a1 = *(const float4*)(ap + 4);
    const float* bp = Bb + (size_t)(k0 + krB) * 256 + nbase + nsB;
    float4 b0 = *(const float4*)bp;
    float4 b1 = *(const float4*)(bp + 4);
    __syncthreads();
    {
      float av[8] = {a0.x, a0.y, a0.z, a0.w, a1.x, a1.y, a1.z, a1.w};
      f16x8 h, l;
#pragma unroll
      for (int j = 0; j < 8; ++j) {
        h[j] = (half_t)av[j];
        l[j] = (half_t)(av[j] - (float)h[j]);
      }
      *(f16x8*)&Ash[srA][ssA] = h;
      *(f16x8*)&Asl[srA][ssA] = l;
      float bv[8] = {b0.x, b0.y, b0.z, b0.w, b1.x, b1.y, b1.z, b1.w};
#pragma unroll
      for (int j = 0; j < 8; ++j) {
        int v = (j + g) & 7;              // bank-stagger across n-groups
        float x = bv[v];
        half_t hi = (half_t)x;
        Bsh[nsB + v][krB] = hi;
        Bsl[nsB + v][krB] = (half_t)(x - (float)hi);
      }
    }
    __syncthreads();
    f16x8 afh[2], afl[2];
#pragma unroll
    for (int i = 0; i < 2; ++i) {
      afh[i] = *(const f16x8*)&Ash[wr + i * 16 + fr][fk];
      afl[i] = *(const f16x8*)&Asl[wr + i * 16 + fr][fk];
    }
#pragma unroll
    for (int nc = 0; nc < 2; ++nc) {
      f16x8 bh8 = *(const f16x8*)&Bsh[wc + nc * 16 + fr][fk];
      f16x8 bl8 = *(const f16x8*)&Bsl[wc + nc * 16 + fr][fk];
#pragma unroll
      for (int i = 0; i < 2; ++i) {
        acc[i][nc] = __builtin_amdgcn_mfma_f32_16x16x32_f16(afh[i], bh8, acc[i][nc], 0, 0, 0);
        acc[i][nc] = __builtin_amdgcn_mfma_f32_16x16x32_f16(afl[i], bh8, acc[i][nc], 0, 0, 0);
        acc[i][nc] = __builtin_amdgcn_mfma_f32_16x16x32_f16(afh[i], bl8, acc[i][nc], 0, 0, 0);
      }
    }
  }
  int rbase = mbase + wr + ((lane >> 4) << 2);
#pragma unroll
  for (int i = 0; i < 2; ++i) {
#pragma unroll
    for (int nc = 0; nc < 2; ++nc) {
      int n = nbase + wc + nc * 16 + fr;
#pragma unroll
      for (int j = 0; j < 4; ++j) {
        int m = rbase + i * 16 + j;
        float c = acoef * acc[i][nc][j];
        if (Eb) c += ecoef * Eb[(size_t)m * 256 + n];
        Cb[(size_t)m * 256 + n] = c;
      }
    }
  }
}

// ---------------- Batched mm (fp32): C = acoef*(A@B) + ecoef*E ---------
__global__ __launch_bounds__(256) void bmm_kernel(
    const float* __restrict__ A, const float* __restrict__ B,
    float* __restrict__ C, int Ndim,
    const float* __restrict__ E, float ecoef, float acoef) {
  int bh = blockIdx.z;
  const float* Ab = A + ((size_t)bh << 16);
  const float* Bb = B + (size_t)bh * 256 * Ndim;
  float* Cb = C + (size_t)bh * 256 * Ndim;
  const float* Eb = E ? (E + (size_t)bh * 256 * Ndim) : nullptr;
  __shared__ float As[16][64];
  __shared__ float Bs[16][64];
  int tid = threadIdx.x;
  int tx = tid & 15, ty = tid >> 4;
  int mbase = blockIdx.y << 6, nbase = blockIdx.x << 6;
  int lr = tid >> 2, lc = tid & 3;
  int bk = tid >> 6, bn = tid & 63;
  float acc[4][4] = {};
  for (int k0 = 0; k0 < 256; k0 += 16) {
    float4 av = *(const float4*)(Ab + (size_t)(mbase + lr) * 256 + k0 + lc * 4);
    float b0 = Bb[(size_t)(k0 + bk) * Ndim + nbase + bn];
    float b1 = Bb[(size_t)(k0 + bk + 4) * Ndim + nbase + bn];
    float b2 = Bb[(size_t)(k0 + bk + 8) * Ndim + nbase + bn];
    float b3 = Bb[(size_t)(k0 + bk + 12) * Ndim + nbase + bn];
    __syncthreads();
    As[lc * 4 + 0][lr] = av.x; As[lc * 4 + 1][lr] = av.y;
    As[lc * 4 + 2][lr] = av.z; As[lc * 4 + 3][lr] = av.w;
    Bs[bk][bn] = b0; Bs[bk + 4][bn] = b1;
    Bs[bk + 8][bn] = b2; Bs[bk + 12][bn] = b3;
    __syncthreads();
#pragma unroll
    for (int kk = 0; kk < 16; ++kk) {
      float4 a4 = *(const float4*)&As[kk][ty * 4];
      float4 b4 = *(const float4*)&Bs[kk][tx * 4];
      acc[0][0] += a4.x * b4.x; acc[0][1] += a4.x * b4.y;
      acc[0][2] += a4.x * b4.z; acc[0][3] += a4.x * b4.w;
      acc[1][0] += a4.y * b4.x; acc[1][1] += a4.y * b4.y;
      acc[1][2] += a4.y * b4.z; acc[1][3] += a4.y * b4.w;
      acc[2][0] += a4.z * b4.x; acc[2][1] += a4.z * b4.y;
      acc[2][2] += a4.z * b4.z; acc[2][3] += a4.z * b4.w;
      acc[3][0] += a4.w * b4.x; acc[3][1] += a4.w * b4.y;
      acc[3][2] += a4.w * b4.z; acc[3][3] += a4.w * b4.w;
    }
  }
#pragma unroll
  for (int i = 0; i < 4; ++i) {
    int m = mbase + ty * 4 + i;
#pragma unroll
    for (int j = 0; j < 4; ++j) {
      int n = nbase + tx * 4 + j;
      float c = acoef * acc[i][j];
      if (Eb) c += ecoef * Eb[(size_t)m * Ndim + n];
      Cb[(size_t)m * Ndim + n] = c;
    }
  }
}

// ---------------- landmark mean pooling (q scaled) + fp16 splits -------
__global__ __launch_bounds__(64) void landmarks_kernel(
    const float* __restrict__ qb,
    const half_t* __restrict__ kh, const half_t* __restrict__ klo,
    float* __restrict__ ql, half_t* __restrict__ qlh, half_t* __restrict__ qll,
    float* __restrict__ klf, half_t* __restrict__ klh, half_t* __restrict__ kll) {
  int blk = blockIdx.x;          // bh*256 + m
  int mm = blk & 255, bh = blk >> 8;
  int b = bh >> 3, h = bh & 7;
  int d = threadIdx.x;
  const float* qbase = qb + ((size_t)(b * NSEQ + mm * 32)) * 512 + h * 64 + d;
  size_t kbase = ((size_t)bh * NSEQ + mm * 32) * 64 + d;
  float sq = 0.f, sk = 0.f;
#pragma unroll 8
  for (int i = 0; i < 32; ++i) {
    sq += qbase[(size_t)i * 512];
    sk += (float)kh[kbase + (size_t)i * 64] + (float)klo[kbase + (size_t)i * 64];
  }
  float qv = sq * (0.03125f * SCALEQ);
  float kvv = sk * 0.03125f;
  size_t o = ((size_t)bh * 256 + mm) * 64 + d;
  ql[o] = qv;
  klf[o] = kvv;
  half_t qhi = (half_t)qv;
  qlh[o] = qhi; qll[o] = (half_t)(qv - (float)qhi);
  half_t khi = (half_t)kvv;
  klh[o] = khi; kll[o] = (half_t)(kvv - (float)khi);
}

// ---------------- attn2 = softmax(q_l @ k_l^T) [bh][256][256] ----------
__global__ __launch_bounds__(256) void attn2_kernel(const float* __restrict__ ql,
    const float* __restrict__ kl, float* __restrict__ a) {
  int bh = blockIdx.y;
  int rbase = blockIdx.x << 5;   // 32 rows
  __shared__ float qs[32][68];
  __shared__ float kst[64][68];  // transposed [d][j]
  __shared__ float sall[32][260];
  int tid = threadIdx.x;
  int r = tid >> 3, g = tid & 7;
  {
    const float* src = ql + ((size_t)bh * 256 + rbase + r) * 64 + g * 8;
    *(float4*)&qs[r][g * 8] = *(const float4*)src;
    *(float4*)&qs[r][g * 8 + 4] = *(const float4*)(src + 4);
  }
  int jl = tid >> 2, i0 = (tid & 3) << 4;
  for (int mc = 0; mc < 4; ++mc) {
    __syncthreads();
    {
      const float* src = kl + ((size_t)bh * 256 + mc * 64 + jl) * 64 + i0;
      float4 k0 = *(const float4*)src;
      float4 k1 = *(const float4*)(src + 4);
      float4 k2 = *(const float4*)(src + 8);
      float4 k3 = *(const float4*)(src + 12);
      TRWR(kst, i0, jl, k0, k1, k2, k3)
    }
    __syncthreads();
    float s0 = 0, s1 = 0, s2 = 0, s3 = 0, s4 = 0, s5 = 0, s6 = 0, s7 = 0;
#pragma unroll 8
    for (int d = 0; d < 64; ++d) {
      float qv = qs[r][d];
      float4 ka = *(const float4*)&kst[d][g * 8];
      float4 kb = *(const float4*)&kst[d][g * 8 + 4];
      s0 += qv * ka.x; s1 += qv * ka.y; s2 += qv * ka.z; s3 += qv * ka.w;
      s4 += qv * kb.x; s5 += qv * kb.y; s6 += qv * kb.z; s7 += qv * kb.w;
    }
    float* dstp = &sall[r][mc * 64 + g * 8];
    dstp[0] = s0; dstp[1] = s1; dstp[2] = s2; dstp[3] = s3;
    dstp[4] = s4; dstp[5] = s5; dstp[6] = s6; dstp[7] = s7;
  }
  __syncthreads();
  float mx = -3.0e38f;
#pragma unroll
  for (int k = 0; k < 32; ++k) mx = fmaxf(mx, sall[r][g + (k << 3)]);
  mx = fmaxf(mx, __shfl_xor(mx, 1));
  mx = fmaxf(mx, __shfl_xor(mx, 2));
  mx = fmaxf(mx, __shfl_xor(mx, 4));
  float sum = 0.f;
#pragma unroll
  for (int k = 0; k < 32; ++k) {
    float p = expf(sall[r][g + (k << 3)] - mx);
    sall[r][g + (k << 3)] = p;
    sum += p;
  }
  sum += __shfl_xor(sum, 1);
  sum += __shfl_xor(sum, 2);
  sum += __shfl_xor(sum, 4);
  float inv = 1.0f / sum;
  float* dst = a + ((size_t)bh * 256 + rbase + r) * 256;
#pragma unroll
  for (int k = 0; k < 32; ++k) dst[g + (k << 3)] = sall[r][g + (k << 3)] * inv;
}

// ---------------- pinv scale = max(rowsum)*max(colsum) ----------------
__global__ void scale_init(unsigned* sbuf) {
  if (threadIdx.x < 2) sbuf[threadIdx.x] = 0u;
}

__global__ __launch_bounds__(256) void scale_reduce(const float* __restrict__ a,
    unsigned* __restrict__ sbuf) {
  int bh = blockIdx.x;
  int tid = threadIdx.x;
  const float* ab = a + ((size_t)bh << 16);
  const float* row = ab + (size_t)tid * 256;
  float rs = 0.f;
  for (int j = 0; j < 256; ++j) rs += fabsf(row[j]);
  float cs = 0.f;
  for (int i = 0; i < 256; ++i) cs += fabsf(ab[((size_t)i << 8) + tid]);
#pragma unroll
  for (int o = 32; o > 0; o >>= 1) {
    rs = fmaxf(rs, __shfl_xor(rs, o));
    cs = fmaxf(cs, __shfl_xor(cs, o));
  }
  __shared__ float redr[4], redc[4];
  int w = tid >> 6;
  if ((tid & 63) == 0) { redr[w] = rs; redc[w] = cs; }
  __syncthreads();
  if (tid == 0) {
    float mr = fmaxf(fmaxf(redr[0], redr[1]), fmaxf(redr[2], redr[3]));
    float mc = fmaxf(fmaxf(redc[0], redc[1]), fmaxf(redc[2], redc[3]));
    atomicMax(sbuf + 0, __float_as_uint(mr));
    atomicMax(sbuf + 1, __float_as_uint(mc));
  }
}

__global__ __launch_bounds__(256) void z0_kernel(const float* __restrict__ a,
    const unsigned* __restrict__ sbuf, float* __restrict__ z) {
  float inv = 1.0f / (__uint_as_float(sbuf[0]) * __uint_as_float(sbuf[1]));
  size_t idx = (size_t)blockIdx.x * 256 + threadIdx.x;
  int bh = (int)(idx >> 16);
  int rem = (int)(idx & 65535);
  int i = rem >> 8, j = rem & 255;
  z[idx] = a[((size_t)bh << 16) + ((size_t)j << 8) + i] * inv;
}

// ==== kv = softmax(q_l @ k^T) @ v  — MFMA flash, split-n x16 ===========
__global__ __launch_bounds__(256) void kv_flash_mfma(
    const half_t* __restrict__ qlh, const half_t* __restrict__ qll,
    const half_t* __restrict__ kh, const half_t* __restrict__ klo,
    const half_t* __restrict__ vth, const half_t* __restrict__ vtl,
    float* __restrict__ po, float* __restrict__ pm, float* __restrict__ pl) {
  __shared__ __align__(16) half_t sKh[4096], sKl[4096], sVh[4096], sVl[4096];
  int sp = blockIdx.x;           // 16 splits of 512 keys
  int qt = blockIdx.y;           // 2 tiles of 128 q
  int bh = blockIdx.z;
  int tid = threadIdx.x;
  int lane = tid & 63, wave = tid >> 6;
  int l15 = lane & 15, lg = lane >> 4;
  int qbase = qt * 128 + wave * 32;
  f16x8 qh[2][2], qlo_[2][2];    // [qsub][ks]
#pragma unroll
  for (int qs = 0; qs < 2; ++qs)
#pragma unroll
    for (int ks = 0; ks < 2; ++ks) {
      size_t off = ((size_t)bh * 256 + qbase + qs * 16 + l15) * 64 + ks * 32 + lg * 8;
      qh[qs][ks] = *(const f16x8*)(qlh + off);
      qlo_[qs][ks] = *(const f16x8*)(qll + off);
    }
  float m_run[2] = {-3.0e38f, -3.0e38f};
  float l_run[2] = {0.f, 0.f};
  f32x4 acc[2][4] = {};
  int sr = tid & 63, sg = tid >> 6;
  int wA = sr * 64 + ((sg * 8) ^ ((sr & 7) << 3));
  int wB = sr * 64 + (((sg + 4) * 8) ^ ((sr & 7) << 3));
  for (int c = 0; c < 8; ++c) {
    int c0 = sp * 512 + c * 64;
    size_t kg = ((size_t)bh * NSEQ + c0 + sr) * 64 + sg * 8;
    size_t vg = ((size_t)bh * 64 + sr) * NSEQ + c0 + sg * 8;
    f16x8 rk0 = *(const f16x8*)(kh + kg);
    f16x8 rk1 = *(const f16x8*)(kh + kg + 32);
    f16x8 rk2 = *(const f16x8*)(klo + kg);
    f16x8 rk3 = *(const f16x8*)(klo + kg + 32);
    f16x8 rv0 = *(const f16x8*)(vth + vg);
    f16x8 rv1 = *(const f16x8*)(vth + vg + 32);
    f16x8 rv2 = *(const f16x8*)(vtl + vg);
    f16x8 rv3 = *(const f16x8*)(vtl + vg + 32);
    __syncthreads();
    *(f16x8*)&sKh[wA] = rk0; *(f16x8*)&sKh[wB] = rk1;
    *(f16x8*)&sKl[wA] = rk2; *(f16x8*)&sKl[wB] = rk3;
    *(f16x8*)&sVh[wA] = rv0; *(f16x8*)&sVh[wB] = rv1;
    *(f16x8*)&sVl[wA] = rv2; *(f16x8*)&sVl[wB] = rv3;
    __syncthreads();
    f32x4 s[2][4] = {};
#pragma unroll
    for (int ks = 0; ks < 2; ++ks) {
#pragma unroll
      for (int ns = 0; ns < 4; ++ns) {
        int r = ns * 16 + l15;
        int off = r * 64 + ((ks * 32 + lg * 8) ^ ((r & 7) << 3));
        f16x8 ah = *(const f16x8*)&sKh[off];
        f16x8 al = *(const f16x8*)&sKl[off];
#pragma unroll
        for (int qs = 0; qs < 2; ++qs) {
          s[qs][ns] = __builtin_amdgcn_mfma_f32_16x16x32_f16(ah, qh[qs][ks], s[qs][ns], 0, 0, 0);
          s[qs][ns] = __builtin_amdgcn_mfma_f32_16x16x32_f16(al, qh[qs][ks], s[qs][ns], 0, 0, 0);
          s[qs][ns] = __builtin_amdgcn_mfma_f32_16x16x32_f16(ah, qlo_[qs][ks], s[qs][ns], 0, 0, 0);
        }
      }
    }
#pragma unroll
    for (int qs = 0; qs < 2; ++qs) {
      float pmax = s[qs][0][0];
#pragma unroll
      for (int ns = 0; ns < 4; ++ns)
#pragma unroll
        for (int j = 0; j < 4; ++j) pmax = fmaxf(pmax, s[qs][ns][j]);
      pmax = fmaxf(pmax, __shfl_xor(pmax, 16));
      pmax = fmaxf(pmax, __shfl_xor(pmax, 32));
      float mnew = fmaxf(m_run[qs], pmax);
      float corr = expf(m_run[qs] - mnew);
      float psum = 0.f;
      f16x4 ph[4], plo_[4];
#pragma unroll
      for (int ns = 0; ns < 4; ++ns)
#pragma unroll
        for (int j = 0; j < 4; ++j) {
          float p = expf(s[qs][ns][j] - mnew);
          psum += p;
          half_t hi = (half_t)p;
          ph[ns][j] = hi;
          plo_[ns][j] = (half_t)(p - (float)hi);
        }
      psum += __shfl_xor(psum, 16);
      psum += __shfl_xor(psum, 32);
      l_run[qs] = l_run[qs] * corr + psum;
      m_run[qs] = mnew;
#pragma unroll
      for (int md = 0; md < 4; ++md) {
        acc[qs][md][0] *= corr; acc[qs][md][1] *= corr;
        acc[qs][md][2] *= corr; acc[qs][md][3] *= corr;
      }
#pragma unroll
      for (int nc = 0; nc < 4; ++nc)
#pragma unroll
        for (int md = 0; md < 4; ++md) {
          int r = md * 16 + l15;
          int off = r * 64 + ((nc * 16 + lg * 4) ^ ((r & 7) << 3));
          f16x4 vh = *(const f16x4*)&sVh[off];
          f16x4 vl = *(const f16x4*)&sVl[off];
          acc[qs][md] = __builtin_amdgcn_mfma_f32_16x16x16f16(vh, ph[nc], acc[qs][md], 0, 0, 0);
          acc[qs][md] = __builtin_amdgcn_mfma_f32_16x16x16f16(vl, ph[nc], acc[qs][md], 0, 0, 0);
          acc[qs][md] = __builtin_amdgcn_mfma_f32_16x16x16f16(vh, plo_[nc], acc[qs][md], 0, 0, 0);
        }
    }
  }
#pragma unroll
  for (int qs = 0; qs < 2; ++qs) {
    size_t row = (size_t)sp * 4096 + bh * 256 + qbase + qs * 16 + l15;
#pragma unroll
    for (int md = 0; md < 4; ++md) {
      float4 o;
      o.x = acc[qs][md][0]; o.y = acc[qs][md][1];
      o.z = acc[qs][md][2]; o.w = acc[qs][md][3];
      *(float4*)&po[row * 64 + md * 16 + lg * 4] = o;
    }
  }
  if (lg == 0) {
#pragma unroll
    for (int qs = 0; qs < 2; ++qs) {
      size_t row = (size_t)sp * 4096 + bh * 256 + qbase + qs * 16 + l15;
      pm[row] = m_run[qs];
      pl[row] = l_run[qs];
    }
  }
}

__global__ __launch_bounds__(64) void kv_combine16(const float* __restrict__ po,
    const float* __restrict__ pm, const float* __restrict__ pl,
    float* __restrict__ kv) {
  int row = blockIdx.x;          // bh*256 + m  (4096)
  int d = threadIdx.x;
  float mg = -3.0e38f;
#pragma unroll
  for (int j = 0; j < 16; ++j) mg = fmaxf(mg, pm[j * 4096 + row]);
  float l = 0.f, o = 0.f;
#pragma unroll
  for (int j = 0; j < 16; ++j) {
    float w = expf(pm[j * 4096 + row] - mg);
    l += pl[j * 4096 + row] * w;
    o += po[((size_t)(j * 4096 + row)) * 64 + d] * w;
  }
  kv[(size_t)row * 64 + d] = o / l;
}

// ---------------- Wm -> Wm^T hi/lo fp16 --------------------------------
__global__ __launch_bounds__(256) void wmsplit_kernel(const float* __restrict__ Wm,
    half_t* __restrict__ wth, half_t* __restrict__ wtl) {
  int idx = blockIdx.x * 256 + threadIdx.x;   // 262144
  int bh = idx >> 14, rem = idx & 16383;
  int m = rem >> 6, dd = rem & 63;
  float v = Wm[idx];
  half_t hi = (half_t)v;
  size_t o = ((size_t)bh * 64 + dd) * 256 + m;
  wth[o] = hi;
  wtl[o] = (half_t)(v - (float)hi);
}

// ---------------- depthwise residual conv (reads V^T splits) -----------
__global__ __launch_bounds__(256) void conv_kernel(
    const half_t* __restrict__ vth, const half_t* __restrict__ vtl,
    const float* __restrict__ w_res, float* __restrict__ outh) {
  int nt = blockIdx.x;           // 128 tiles of 64 rows
  int bh = blockIdx.y;           // 16
  int b = bh >> 3, h = bh & 7;
  __shared__ float vsh[64][97];
  __shared__ float wsh[33];
  int tid = threadIdx.x;
  if (tid < 33) wsh[tid] = w_res[h * 33 + tid];
  int nbase = nt << 6;
  {
    int d = tid >> 2, part = tid & 3;
    const half_t* vh = vth + ((size_t)bh * 64 + d) * NSEQ;
    const half_t* vl = vtl + ((size_t)bh * 64 + d) * NSEQ;
#pragma unroll
    for (int i8 = 0; i8 < 3; ++i8) {
      int colbase = part * 24 + i8 * 8;
      int n0 = nbase - 16 + colbase;
      if (n0 >= 0 && n0 + 8 <= NSEQ) {
        f16x8 a = *(const f16x8*)(vh + n0);
        f16x8 bb = *(const f16x8*)(vl + n0);
#pragma unroll
        for (int j = 0; j < 8; ++j) vsh[d][colbase + j] = (float)a[j] + (float)bb[j];
      } else {
#pragma unroll
        for (int j = 0; j < 8; ++j) {
          int n = n0 + j;
          vsh[d][colbase + j] = (n >= 0 && n < NSEQ)
              ? ((float)vh[n] + (float)vl[n]) : 0.f;
        }
      }
    }
  }
  __syncthreads();
  int d = tid & 63, rg = tid >> 6;
#pragma unroll
  for (int rr = 0; rr < 16; ++rr) {
    int r = rg * 16 + rr;
    float acc = 0.f;
#pragma unroll
    for (int k = 0; k < 33; ++k) acc += vsh[d][r + k] * wsh[k];
    outh[((size_t)(b * NSEQ + nbase + r)) * 512 + h * 64 + d] = acc;
  }
}

// ==== outh += softmax(q @ k_l^T) @ Wm — MFMA, same structure ===========
__global__ __launch_bounds__(256) void attn1_mfma(
    const float* __restrict__ qb,
    const half_t* __restrict__ klh, const half_t* __restrict__ kll,
    const half_t* __restrict__ wth, const half_t* __restrict__ wtl,
    float* __restrict__ outh) {
  __shared__ __align__(16) half_t sKh[4096], sKl[4096], sVh[4096], sVl[4096];
  int qt = blockIdx.x;           // 64 tiles of 128 q
  int bh = blockIdx.y;
  int b8 = (bh >> 3) * NSEQ;
  int h = bh & 7;
  int tid = threadIdx.x;
  int lane = tid & 63, wave = tid >> 6;
  int l15 = lane & 15, lg = lane >> 4;
  int qbase = qt * 128 + wave * 32;
  f16x8 qh[2][2], qlo_[2][2];
#pragma unroll
  for (int qs = 0; qs < 2; ++qs)
#pragma unroll
    for (int ks = 0; ks < 2; ++ks) {
      const float* src = qb + ((size_t)(b8 + qbase + qs * 16 + l15)) * 512
                       + h * 64 + ks * 32 + lg * 8;
      float4 f0 = *(const float4*)src;
      float4 f1 = *(const float4*)(src + 4);
      float v[8] = {f0.x, f0.y, f0.z, f0.w, f1.x, f1.y, f1.z, f1.w};
      f16x8 hh, ll;
#pragma unroll
      for (int j = 0; j < 8; ++j) {
        float sv = v[j] * SCALEQ;
        half_t hi = (half_t)sv;
        hh[j] = hi;
        ll[j] = (half_t)(sv - (float)hi);
      }
      qh[qs][ks] = hh;
      qlo_[qs][ks] = ll;
    }
  float m_run[2] = {-3.0e38f, -3.0e38f};
  float l_run[2] = {0.f, 0.f};
  f32x4 acc[2][4] = {};
  int sr = tid & 63, sg = tid >> 6;
  int wA = sr * 64 + ((sg * 8) ^ ((sr & 7) << 3));
  int wB = sr * 64 + (((sg + 4) * 8) ^ ((sr & 7) << 3));
  for (int c = 0; c < 4; ++c) {
    int c0 = c * 64;
    size_t kg = ((size_t)bh * 256 + c0 + sr) * 64 + sg * 8;
    size_t vg = ((size_t)bh * 64 + sr) * 256 + c0 + sg * 8;
    f16x8 rk0 = *(const f16x8*)(klh + kg);
    f16x8 rk1 = *(const f16x8*)(klh + kg + 32);
    f16x8 rk2 = *(const f16x8*)(kll + kg);
    f16x8 rk3 = *(const f16x8*)(kll + kg + 32);
    f16x8 rv0 = *(const f16x8*)(wth + vg);
    f16x8 rv1 = *(const f16x8*)(wth + vg + 32);
    f16x8 rv2 = *(const f16x8*)(wtl + vg);
    f16x8 rv3 = *(const f16x8*)(wtl + vg + 32);
    __syncthreads();
    *(f16x8*)&sKh[wA] = rk0; *(f16x8*)&sKh[wB] = rk1;
    *(f16x8*)&sKl[wA] = rk2; *(f16x8*)&sKl[wB] = rk3;
    *(f16x8*)&sVh[wA] = rv0; *(f16x8*)&sVh[wB] = rv1;
    *(f16x8*)&sVl[wA] = rv2; *(f16x8*)&sVl[wB] = rv3;
    __syncthreads();
    f32x4 s[2][4] = {};
#pragma unroll
    for (int ks = 0; ks < 2; ++ks) {
#pragma unroll
      for (int ns = 0; ns < 4; ++ns) {
        int r = ns * 16 + l15;
        int off = r * 64 + ((ks * 32 + lg * 8) ^ ((r & 7) << 3));
        f16x8 ah = *(const f16x8*)&sKh[off];
        f16x8 al = *(const f16x8*)&sKl[off];
#pragma unroll
        for (int qs = 0; qs < 2; ++qs) {
          s[qs][ns] = __builtin_amdgcn_mfma_f32_16x16x32_f16(ah, qh[qs][ks], s[qs][ns], 0, 0, 0);
          s[qs][ns] = __builtin_amdgcn_mfma_f32_16x16x32_f16(al, qh[qs][ks], s[qs][ns], 0, 0, 0);
          s[qs][ns] = __builtin_amdgcn_mfma_f32_16x16x32_f16(ah, qlo_[qs][ks], s[qs][ns], 0, 0, 0);
        }
      }
    }
#pragma unroll
    for (int qs = 0; qs < 2; ++qs) {
      float pmax = s[qs][0][0];
#pragma unroll
      for (int ns = 0; ns < 4; ++ns)
#pragma unroll
        for (int j = 0; j < 4; ++j) pmax = fmaxf(pmax, s[qs][ns][j]);
      pmax = fmaxf(pmax, __shfl_xor(pmax, 16));
      pmax = fmaxf(pmax, __shfl_xor(pmax, 32));
      float mnew = fmaxf(m_run[qs], pmax);
      float corr = expf(m_run[qs] - mnew);
      float psum = 0.f;
      f16x4 ph[4], plo_[4];
#pragma unroll
      for (int ns = 0; ns < 4; ++ns)
#pragma unroll
        for (int j = 0; j < 4; ++j) {
          float p = expf(s[qs][ns][j] - mnew);
          psum += p;
          half_t hi = (half_t)p;
          ph[ns][j] = hi;
          plo_[ns][j] = (half_t)(p - (float)hi);
        }
      psum += __shfl_xor(psum, 16);
      psum += __shfl_xor(psum, 32);
      l_run[qs] = l_run[qs] * corr + psum;
      m_run[qs] = mnew;
#pragma unroll
      for (int md = 0; md < 4; ++md) {
        acc[qs][md][0] *= corr; acc[qs][md][1] *= corr;
        acc[qs][md][2] *= corr; acc[qs][md][3] *= corr;
      }
#pragma unroll
      for (int nc = 0; nc < 4; ++nc)
#pragma unroll
        for (int md = 0; md < 4; ++md) {
          int r = md * 16 + l15;
          int off = r * 64 + ((nc * 16 + lg * 4) ^ ((r & 7) << 3));
          f16x4 vh = *(const f16x4*)&sVh[off];
          f16x4 vl = *(const f16x4*)&sVl[off];
          acc[qs][md] = __builtin_amdgcn_mfma_f32_16x16x16f16(vh, ph[nc], acc[qs][md], 0, 0, 0);
          acc[qs][md] = __builtin_amdgcn_mfma_f32_16x16x16f16(vl, ph[nc], acc[qs][md], 0, 0, 0);
          acc[qs][md] = __builtin_amdgcn_mfma_f32_16x16x16f16(vh, plo_[nc], acc[qs][md], 0, 0, 0);
        }
    }
  }
#pragma unroll
  for (int qs = 0; qs < 2; ++qs) {
    float linv = 1.0f / l_run[qs];
    size_t nrow = (size_t)(b8 + qbase + qs * 16 + l15);
#pragma unroll
    for (int md = 0; md < 4; ++md) {
      float* dst = outh + nrow * 512 + h * 64 + md * 16 + lg * 4;
      float4 e = *(float4*)dst;
      e.x += acc[qs][md][0] * linv;
      e.y += acc[qs][md][1] * linv;
      e.z += acc[qs][md][2] * linv;
      e.w += acc[qs][md][3] * linv;
      *(float4*)dst = e;
    }
  }
}

// ======================================================================
extern "C" void kernel_launch(void* const* d_in, const int* in_sizes, int n_in,
                              void* d_out, int out_size, void* d_ws, size_t ws_size,
                              hipStream_t stream) {
  (void)in_sizes; (void)n_in; (void)out_size; (void)ws_size;
  const float* x     = (const float*)d_in[0];
  const float* gamma = (const float*)d_in[1];
  const float* beta  = (const float*)d_in[2];
  const float* w_qkv = (const float*)d_in[3];
  const float* w_out = (const float*)d_in[4];
  const float* b_out = (const float*)d_in[5];
  const float* w_res = (const float*)d_in[6];
  float* out = (float*)d_out;
  float* ws = (float*)d_ws;

  // ---- workspace layout (float offsets) ----
  float* qb    = ws;                           // [0 .. 8,388,608) q fp32
  half_t* kh   = (half_t*)(ws + 8388608);      // K hi  [bh][8192][64]
  half_t* klo  = (half_t*)(ws + 12582912);     // K lo
  half_t* vth  = (half_t*)(ws + 16777216);     // V^T hi [bh][64][8192]
  half_t* vtl  = (half_t*)(ws + 20971520);     // V^T lo
  float* xreg  = ws + 25165824;                // 8.39M multi-use region
  half_t* xh   = (half_t*)xreg;                // ln out hi (dead after qkv gemm)
  half_t* xl   = (half_t*)(ws + 29360128);     // ln out lo
  float* A2    = xreg;                         // pinv temps overlay xreg
  float* Z0    = xreg + 1048576;
  float* Z1    = xreg + 2097152;
  float* AZ    = xreg + 3145728;
  float* TT    = xreg + 4194304;
  float* UU    = xreg + 5242880;
  float* po    = xreg + 2097152;               // overlays Z1..UU (dead post-pinv)
  float* pm    = xreg + 6291456;
  float* pl    = xreg + 6356992;
  half_t* qlh  = (half_t*)(xreg + 6422528);    // q_l hi/lo (dead before outh)
  half_t* qll  = (half_t*)(xreg + 6553600);
  float* outh  = xreg;                         // overlays all xreg post-Wm
  half_t* wq_h = (half_t*)(ws + 33554432);     // dead after qkv gemm
  half_t* wq_l = (half_t*)(ws + 33947648);     // dead after qkv gemm
  half_t* wo_h = (half_t*)(ws + 34340864);
  half_t* wo_l = (half_t*)(ws + 34471936);
  half_t* klh  = wq_h;                         // reuse wq_h region
  half_t* kll  = (half_t*)(ws + 33685504);
  half_t* wmt_h = wq_l;                        // reuse wq_l region
  half_t* wmt_l = (half_t*)(ws + 34078720);
  float* ql    = ws + 34603008;                // q_l fp32 (attn2)
  float* klf   = ws + 34865152;                // k_l fp32 (attn2)
  float* kv    = ws + 35127296;
  float* Wm    = ws + 35389440;
  unsigned* sbuf = (unsigned*)(ws + 35651584);
  half_t* oh_h = (half_t*)ws;                  // overlays qb (dead post-attn1)
  half_t* oh_l = (half_t*)(ws + 4194304);

  ln_kernel<<<16384, 64, 0, stream>>>(x, gamma, beta, xh, xl);
  split_kernel<<<768, 256, 0, stream>>>(w_qkv, wq_h, wq_l, 196608);
  split_kernel<<<256, 256, 0, stream>>>(w_out, wo_h, wo_l, 65536);

  gemm_mfma_qkv<<<dim3(12, 128), 256, 0, stream>>>(
      xh, xl, wq_h, wq_l, 512, qb, kh, klo, vth, vtl);

  landmarks_kernel<<<4096, 64, 0, stream>>>(qb, kh, klo, ql, qlh, qll, klf, klh, kll);

  attn2_kernel<<<dim3(8, 16), 256, 0, stream>>>(ql, klf, A2);

  scale_init<<<1, 64, 0, stream>>>(sbuf);
  scale_reduce<<<16, 256, 0, stream>>>(A2, sbuf);
  z0_kernel<<<4096, 256, 0, stream>>>(A2, sbuf, Z0);

  float* zc = Z0;
  float* zn = Z1;
  for (int it = 0; it < 6; ++it) {
    dim3 gb(4, 4, 16);
    bmm_mfma<<<gb, 256, 0, stream>>>(A2, zc, AZ, nullptr, 0.f, 1.f);
    bmm_mfma<<<gb, 256, 0, stream>>>(AZ, AZ, TT, AZ, 7.f, -1.f);
    bmm_mfma<<<gb, 256, 0, stream>>>(AZ, TT, UU, AZ, 15.f, -1.f);
    bmm_mfma<<<gb, 256, 0, stream>>>(zc, UU, zn, zc, 3.25f, -0.25f);
    float* t = zc; zc = zn; zn = t;
  }
  // zc == Z0 after 6 iterations

  kv_flash_mfma<<<dim3(16, 2, 16), 256, 0, stream>>>(
      qlh, qll, kh, klo, vth, vtl, po, pm, pl);
  kv_combine16<<<4096, 64, 0, stream>>>(po, pm, pl, kv);

  // W = pinv @ kv   [bh][256][64]
  bmm_kernel<<<dim3(1, 4, 16), 256, 0, stream>>>(zc, kv, Wm, 64, nullptr, 0.f, 1.f);
  wmsplit_kernel<<<1024, 256, 0, stream>>>(Wm, wmt_h, wmt_l);

  conv_kernel<<<dim3(128, 16), 256, 0, stream>>>(vth, vtl, w_res, outh);
  attn1_mfma<<<dim3(64, 16), 256, 0, stream>>>(qb, klh, kll, wmt_h, wmt_l, outh);

  split_kernel<<<8192, 256, 0, stream>>>(outh, oh_h, oh_l, 2097152);

  gemm_mfma_out<<<dim3(4, 128), 256, 0, stream>>>(
      oh_h, oh_l, wo_h, wo_l, out, 512, 512, x, b_out);
}